// Round 13
// baseline (439.295 us; speedup 1.0000x reference)
//
#include <hip/hip_runtime.h>
#include <math.h>
#include <float.h>

#define BATCH 4
#define CH    256
#define NT    4096
#define NCTX  8192
#define KI    8

// coarse-selection geometry
#define CSEL    10                 // per-split top-C after lane-half merge (>=8+2 slack => safe)
#define DNSPLIT 8                  // ctx splits
#define CTX_PER (NCTX / DNSPLIT)   // 1024
#define NTILE   (CTX_PER / 32)     // 32 tiles of 32 ctx
#define NKEY    (DNSPLIT * CSEL)   // 80 packed keys per target
#define RESC    12                 // keys kept for exact fp64 rescore

typedef __attribute__((ext_vector_type(8)))  __bf16 bf16x8;
typedef __attribute__((ext_vector_type(16))) float  f32x16;

__device__ __forceinline__ unsigned short bf16_rne(float v) {
  unsigned u = __float_as_uint(v);
  return (unsigned short)((u + 0x7fffu + ((u >> 16) & 1u)) >> 16);
}

// ---------------- prep: transpose (128-ch tiles, wide stores) + W transpose, role-fused ----------------
__global__ __launch_bounds__(256) void k_prep(const float* __restrict__ Xt,
                                              const float* __restrict__ Xc1,
                                              const float* __restrict__ Xc2,
                                              float* __restrict__ Q,
                                              float* __restrict__ P,
                                              unsigned short* __restrict__ XtBh,
                                              unsigned short* __restrict__ XtBl,
                                              unsigned short* __restrict__ XcBh,
                                              unsigned short* __restrict__ XcBl,
                                              float* __restrict__ nrm,
                                              const float* __restrict__ W1,
                                              const float* __restrict__ W2,
                                              unsigned short* __restrict__ WT1h,
                                              unsigned short* __restrict__ WT1l,
                                              unsigned short* __restrict__ WT2h,
                                              unsigned short* __restrict__ WT2l) {
  __shared__ float tile[128][33];   // 16.9 KB
  __shared__ float ps[8][32];
  const int bid = blockIdx.x;
  const int tx = threadIdx.x, ty = threadIdx.y;

  if (bid < 3072) {
    const int x = bid & 127, y = (bid >> 7) & 1, z = bid >> 8;
    const int which = z >> 2, b = z & 3;
    const float* src;
    float* dF; unsigned short *dH, *dL; float* nrmp = nullptr;
    if (which == 0) {
      src = Xt + (long)b * CH * NT;
      dF = Q + (long)b * NT * CH;
      dH = XtBh + (long)b * NT * CH;  dL = XtBl + (long)b * NT * CH;
    } else if (which == 1) {
      src = Xc1 + (long)b * CH * NT;
      dF = P + (long)b * NCTX * CH;
      dH = XcBh + (long)b * NCTX * CH;  dL = XcBl + (long)b * NCTX * CH;
      nrmp = nrm + (long)b * NCTX;
    } else {
      src = Xc2 + (long)b * CH * NT;
      dF = P + ((long)b * NCTX + NT) * CH;
      dH = XcBh + ((long)b * NCTX + NT) * CH;  dL = XcBl + ((long)b * NCTX + NT) * CH;
      nrmp = nrm + (long)b * NCTX + NT;
    }
    const int m0 = x * 32, c0 = y * 128;
    float part = 0.f;
#pragma unroll
    for (int i = ty; i < 128; i += 8) {
      float v = src[(long)(c0 + i) * NT + (m0 + tx)];
      tile[i][tx] = v;
      part = fmaf(v, v, part);
    }
    if (which) ps[ty][tx] = part;
    __syncthreads();
#pragma unroll
    for (int i = ty; i < 32; i += 8) {
      float v0 = tile[4 * tx + 0][i];
      float v1 = tile[4 * tx + 1][i];
      float v2 = tile[4 * tx + 2][i];
      float v3 = tile[4 * tx + 3][i];
      long o = (long)(m0 + i) * CH + (c0 + 4 * tx);
      float4 f4; f4.x = v0; f4.y = v1; f4.z = v2; f4.w = v3;
      *(float4*)&dF[o] = f4;
      unsigned short h0 = bf16_rne(v0), h1 = bf16_rne(v1), h2 = bf16_rne(v2), h3 = bf16_rne(v3);
      ushort4 h4; h4.x = h0; h4.y = h1; h4.z = h2; h4.w = h3;
      *(ushort4*)&dH[o] = h4;
      ushort4 l4;
      l4.x = bf16_rne(v0 - __uint_as_float((unsigned)h0 << 16));
      l4.y = bf16_rne(v1 - __uint_as_float((unsigned)h1 << 16));
      l4.z = bf16_rne(v2 - __uint_as_float((unsigned)h2 << 16));
      l4.w = bf16_rne(v3 - __uint_as_float((unsigned)h3 << 16));
      *(ushort4*)&dL[o] = l4;
    }
    if (which && ty == 0) {
      float s = 0.f;
#pragma unroll
      for (int j = 0; j < 8; ++j) s += ps[j][tx];
      atomicAdd(&nrmp[m0 + tx], -0.5f * s);
    }
  } else {
    const int r = bid - 3072;
    const int n0 = (r & 7) * 32, k0 = ((r >> 3) & 7) * 32;
    const float* W = (r >> 6) ? W2 : W1;
    unsigned short* WTh = (r >> 6) ? WT2h : WT1h;
    unsigned short* WTl = (r >> 6) ? WT2l : WT1l;
#pragma unroll
    for (int i = ty; i < 32; i += 8)
      tile[i][tx] = W[(k0 + i) * CH + (n0 + tx)];
    __syncthreads();
#pragma unroll
    for (int i = ty; i < 32; i += 8) {
      float v = tile[tx][i];
      int o = (n0 + i) * CH + (k0 + tx);
      unsigned short h = bf16_rne(v);
      WTh[o] = h;
      WTl[o] = bf16_rne(v - __uint_as_float((unsigned)h << 16));
    }
  }
}

// ---------------- main: dist + gemm roles, INTERLEAVED (fatmode) for co-residency ----------------
// fatmode: group=bid/5, slot=bid%5; slot<2 -> dist lid=group*2+slot; else gemm gid=group*3+slot-2.
// !fatmode: all blocks dist, lid=bid.
__global__ __launch_bounds__(256) void k_main(const __bf16* __restrict__ XcB,
                                              const __bf16* __restrict__ XtB,
                                              const float* __restrict__ nrm,
                                              unsigned* __restrict__ cand,
                                              const unsigned short* __restrict__ XtBh,
                                              const unsigned short* __restrict__ XtBl,
                                              const unsigned short* __restrict__ XcBh,
                                              const unsigned short* __restrict__ XcBl,
                                              const unsigned short* __restrict__ WTh,
                                              const unsigned short* __restrict__ WTl,
                                              const float* __restrict__ bias,
                                              float* __restrict__ outT,
                                              float* __restrict__ outC,
                                              int fatmode) {
  __shared__ __bf16 lds[2][32 * CH];   // 32 KB, shared by both roles
  const int bid = blockIdx.x;
  const int t = threadIdx.x, w = t >> 6, lane = t & 63;
  const int l31 = lane & 31, lh = lane >> 5;

  int lid = bid, gid = -1;
  if (fatmode) {
    const int group = bid / 5, slot = bid % 5;
    if (slot < 2) lid = group * 2 + slot;
    else { lid = -1; gid = group * 3 + (slot - 2); }
  }

  if (gid < 0) {
    // ---- dist role ----
    const int xk = lid & 7;
    const int b = xk >> 1, jh = xk & 1;
    const int jw = (lid >> 3) & 15, split = lid >> 7;
    const int tgt0 = (jh * 16 + jw) * 128 + w * 32;
    const int cbase = split * CTX_PER;
    const float* nrmt = nrm + (long)b * NCTX + cbase;

    const __bf16* tp = XtB + ((long)b * NT + tgt0 + l31) * CH + lh * 8;
    bf16x8 bfrag[16];
#pragma unroll
    for (int s = 0; s < 16; ++s) bfrag[s] = *(const bf16x8*)(tp + s * 16);

    unsigned kd[CSEL];
#pragma unroll
    for (int q = 0; q < CSEL; ++q) kd[q] = 0xFFFFFFFFu;

    const __bf16* cp = XcB + ((long)b * NCTX + cbase + l31) * CH;

    auto STAGE = [&](int buf, int jt) {
#pragma unroll
      for (int r = 0; r < 4; ++r) {
        int c = r * 4 + w;
        const __bf16* src = cp + (long)jt * 32 * CH + (c * 2 + lh) * 8;
        __bf16* dst = &lds[buf][c * 512];
        __builtin_amdgcn_global_load_lds((const __attribute__((address_space(1))) void*)src,
                                         (__attribute__((address_space(3))) void*)dst,
                                         16, 0, 0);
      }
    };

    STAGE(0, 0);
    __syncthreads();

    int cur = 0;
    for (int jt = 0; jt < NTILE; ++jt) {
      if (jt + 1 < NTILE) STAGE(cur ^ 1, jt + 1);

      const int ct0 = jt * 32;
      f32x16 acc;
#pragma unroll
      for (int g = 0; g < 4; ++g) {
        float4 nv = *(const float4*)&nrmt[ct0 + 8 * g + 4 * lh];
        acc[4 * g + 0] = nv.x; acc[4 * g + 1] = nv.y;
        acc[4 * g + 2] = nv.z; acc[4 * g + 3] = nv.w;
      }
#pragma unroll
      for (int s = 0; s < 16; ++s) {
        bf16x8 a = *(const bf16x8*)(&lds[cur][s * 512 + lane * 8]);
        acc = __builtin_amdgcn_mfma_f32_32x32x16_bf16(a, bfrag[s], acc, 0, 0, 0);
      }

#pragma unroll
      for (int reg = 0; reg < 16; ++reg) {
        const int row = (reg & 3) + 8 * (reg >> 2) + lh * 4;
        float sc = fmaf(acc[reg], -2.0f, 512.0f);
        unsigned key = (__float_as_uint(sc) & 0xFFFFF800u) | (unsigned)ct0 | (unsigned)row;
#pragma unroll
        for (int q = 0; q < CSEL; ++q) {
          unsigned lo = min(key, kd[q]);
          key = max(key, kd[q]);
          kd[q] = lo;
        }
      }
      __syncthreads();
      cur ^= 1;
    }

    unsigned oth[CSEL];
#pragma unroll
    for (int q = 0; q < CSEL; ++q) oth[q] = (unsigned)__shfl_xor((int)kd[q], 32, 64);
    if (lh == 0) {
      long ob = (((long)b * NT + tgt0 + l31) * DNSPLIT + split) * CSEL;
#pragma unroll
      for (int q = 0; q < CSEL; ++q)
        cand[ob + q] = min(kd[q], oth[CSEL - 1 - q]);
    }
  } else {
    // ---- gemm role (fat mode only) ----
    int g = gid;
    const unsigned short *Ah, *Al; float* out; int M, m0, b;
    if (g < 512) { Ah = XtBh; Al = XtBl; out = outT; M = NT;   m0 = (g & 127) * 32; b = g >> 7; }
    else { g -= 512; Ah = XcBh; Al = XcBl; out = outC; M = NCTX; m0 = (g & 255) * 32; b = g >> 8; }
    __bf16* ldsH = lds[0];
    __bf16* ldsL = lds[1];
    const long abase = (long)b * M * CH;
    const unsigned short* pH = Ah + abase + (long)(m0 + l31) * CH;
    const unsigned short* pL = Al + abase + (long)(m0 + l31) * CH;
#pragma unroll
    for (int r = 0; r < 4; ++r) {
      int c = r * 4 + w;
      __builtin_amdgcn_global_load_lds(
          (const __attribute__((address_space(1))) void*)(pH + (c * 2 + lh) * 8),
          (__attribute__((address_space(3))) void*)&ldsH[c * 512], 16, 0, 0);
      __builtin_amdgcn_global_load_lds(
          (const __attribute__((address_space(1))) void*)(pL + (c * 2 + lh) * 8),
          (__attribute__((address_space(3))) void*)&ldsL[c * 512], 16, 0, 0);
    }
    __syncthreads();

    const int n0 = w * 64;
    f32x16 acc0, acc1;
#pragma unroll
    for (int i = 0; i < 16; ++i) { acc0[i] = 0.f; acc1[i] = 0.f; }
#pragma unroll
    for (int s = 0; s < 16; ++s) {
      bf16x8 ah = *(const bf16x8*)&ldsH[s * 512 + lane * 8];
      bf16x8 al = *(const bf16x8*)&ldsL[s * 512 + lane * 8];
      const int koff = lh * 8 + s * 16;
      bf16x8 bh0 = *(const bf16x8*)&WTh[(n0 + l31) * CH + koff];
      bf16x8 bl0 = *(const bf16x8*)&WTl[(n0 + l31) * CH + koff];
      bf16x8 bh1 = *(const bf16x8*)&WTh[(n0 + 32 + l31) * CH + koff];
      bf16x8 bl1 = *(const bf16x8*)&WTl[(n0 + 32 + l31) * CH + koff];
      acc0 = __builtin_amdgcn_mfma_f32_32x32x16_bf16(ah, bh0, acc0, 0, 0, 0);
      acc1 = __builtin_amdgcn_mfma_f32_32x32x16_bf16(ah, bh1, acc1, 0, 0, 0);
      acc0 = __builtin_amdgcn_mfma_f32_32x32x16_bf16(ah, bl0, acc0, 0, 0, 0);
      acc1 = __builtin_amdgcn_mfma_f32_32x32x16_bf16(ah, bl1, acc1, 0, 0, 0);
      acc0 = __builtin_amdgcn_mfma_f32_32x32x16_bf16(al, bh0, acc0, 0, 0, 0);
      acc1 = __builtin_amdgcn_mfma_f32_32x32x16_bf16(al, bh1, acc1, 0, 0, 0);
    }
    float* ob = out + abase;
    float bi0 = bias[n0 + l31], bi1 = bias[n0 + 32 + l31];
#pragma unroll
    for (int reg = 0; reg < 16; ++reg) {
      int row = (reg & 3) + 8 * (reg >> 2) + 4 * lh;
      ob[(long)(m0 + row) * CH + n0 + l31]      = acc0[reg] + bi0;
      ob[(long)(m0 + row) * CH + n0 + 32 + l31] = acc1[reg] + bi1;
    }
  }
}

// ---------------- standalone node2edge GEMM (fallback mode) ----------------
__global__ __launch_bounds__(256) void k_gemm_mfma(const unsigned short* __restrict__ Ah,
                                                   const unsigned short* __restrict__ Al,
                                                   const unsigned short* __restrict__ WTh,
                                                   const unsigned short* __restrict__ WTl,
                                                   const float* __restrict__ bias,
                                                   float* __restrict__ out, int M) {
  __shared__ __bf16 ldsH[32 * CH];
  __shared__ __bf16 ldsL[32 * CH];
  const int b = blockIdx.y;
  const int m0 = blockIdx.x * 32;
  const int t = threadIdx.x, w = t >> 6, lane = t & 63;
  const int l31 = lane & 31, lh = lane >> 5;
  const long abase = (long)b * M * CH;
  const unsigned short* pH = Ah + abase + (long)(m0 + l31) * CH;
  const unsigned short* pL = Al + abase + (long)(m0 + l31) * CH;
#pragma unroll
  for (int r = 0; r < 4; ++r) {
    int c = r * 4 + w;
    __builtin_amdgcn_global_load_lds(
        (const __attribute__((address_space(1))) void*)(pH + (c * 2 + lh) * 8),
        (__attribute__((address_space(3))) void*)&ldsH[c * 512], 16, 0, 0);
    __builtin_amdgcn_global_load_lds(
        (const __attribute__((address_space(1))) void*)(pL + (c * 2 + lh) * 8),
        (__attribute__((address_space(3))) void*)&ldsL[c * 512], 16, 0, 0);
  }
  __syncthreads();

  const int n0 = w * 64;
  f32x16 acc0, acc1;
#pragma unroll
  for (int i = 0; i < 16; ++i) { acc0[i] = 0.f; acc1[i] = 0.f; }
#pragma unroll
  for (int s = 0; s < 16; ++s) {
    bf16x8 ah = *(const bf16x8*)&ldsH[s * 512 + lane * 8];
    bf16x8 al = *(const bf16x8*)&ldsL[s * 512 + lane * 8];
    const int koff = lh * 8 + s * 16;
    bf16x8 bh0 = *(const bf16x8*)&WTh[(n0 + l31) * CH + koff];
    bf16x8 bl0 = *(const bf16x8*)&WTl[(n0 + l31) * CH + koff];
    bf16x8 bh1 = *(const bf16x8*)&WTh[(n0 + 32 + l31) * CH + koff];
    bf16x8 bl1 = *(const bf16x8*)&WTl[(n0 + 32 + l31) * CH + koff];
    acc0 = __builtin_amdgcn_mfma_f32_32x32x16_bf16(ah, bh0, acc0, 0, 0, 0);
    acc1 = __builtin_amdgcn_mfma_f32_32x32x16_bf16(ah, bh1, acc1, 0, 0, 0);
    acc0 = __builtin_amdgcn_mfma_f32_32x32x16_bf16(ah, bl0, acc0, 0, 0, 0);
    acc1 = __builtin_amdgcn_mfma_f32_32x32x16_bf16(ah, bl1, acc1, 0, 0, 0);
    acc0 = __builtin_amdgcn_mfma_f32_32x32x16_bf16(al, bh0, acc0, 0, 0, 0);
    acc1 = __builtin_amdgcn_mfma_f32_32x32x16_bf16(al, bh1, acc1, 0, 0, 0);
  }
  float* ob = out + abase;
  float bi0 = bias[n0 + l31], bi1 = bias[n0 + 32 + l31];
#pragma unroll
  for (int reg = 0; reg < 16; ++reg) {
    int row = (reg & 3) + 8 * (reg >> 2) + 4 * lh;
    ob[(long)(m0 + row) * CH + n0 + l31]      = acc0[reg] + bi0;
    ob[(long)(m0 + row) * CH + n0 + 32 + l31] = acc1[reg] + bi1;
  }
}

// ---------------- rescore: 4 targets/block, coarse top-RESC of 80 keys, fp64 exact, rank-8 + counts ----------------
__global__ __launch_bounds__(256) void k_rescore(const float* __restrict__ XtT,
                                                 const float* __restrict__ XcT,
                                                 const unsigned* __restrict__ cand,
                                                 int* __restrict__ knn,
                                                 unsigned* __restrict__ counts) {
  const int t = threadIdx.x, sub = t >> 6, lane = t & 63;
  const int n = blockIdx.x * 4 + sub, b = blockIdx.y;
  const int grp = lane >> 4, gl = lane & 15;
  __shared__ unsigned sk[4][NKEY];
  __shared__ int cidx[4][RESC];
  __shared__ double sd[4][RESC];
  __shared__ int sj[4][RESC];
  const unsigned* kp = cand + ((long)b * NT + n) * NKEY;
  unsigned k0 = kp[lane];
  unsigned k1 = (lane < NKEY - 64) ? kp[64 + lane] : 0xFFFFFFFFu;
  sk[sub][lane] = k0;
  if (lane < NKEY - 64) sk[sub][64 + lane] = k1;
  __syncthreads();
  int r0 = 0, r1 = 0;
  for (int i = 0; i < NKEY; ++i) {
    unsigned s = sk[sub][i];
    r0 += (s < k0 || (s == k0 && i < lane)) ? 1 : 0;
    r1 += (s < k1 || (s == k1 && i < 64 + lane)) ? 1 : 0;
  }
  if (r0 < RESC) cidx[sub][r0] = (lane / CSEL) * CTX_PER + (int)(k0 & 0x7FFu);
  if (lane < NKEY - 64 && r1 < RESC)
    cidx[sub][r1] = ((64 + lane) / CSEL) * CTX_PER + (int)(k1 & 0x7FFu);
  __syncthreads();

  const float* xt = XtT + ((long)b * NT + n) * CH + gl * 16;
  double xa[16];
#pragma unroll
  for (int r = 0; r < 4; ++r) {
    float4 v = *(const float4*)(xt + r * 4);
    xa[4 * r + 0] = (double)v.x; xa[4 * r + 1] = (double)v.y;
    xa[4 * r + 2] = (double)v.z; xa[4 * r + 3] = (double)v.w;
  }
#pragma unroll
  for (int q0 = 0; q0 < RESC; q0 += 4) {
    int q = q0 + grp;
    int j = cidx[sub][q];
    const float* xc = XcT + ((long)b * NCTX + j) * CH + gl * 16;
    double acc = 0.0;
#pragma unroll
    for (int r = 0; r < 4; ++r) {
      float4 v = *(const float4*)(xc + r * 4);
      double d0 = xa[4 * r + 0] - (double)v.x; acc = fma(d0, d0, acc);
      double d1 = xa[4 * r + 1] - (double)v.y; acc = fma(d1, d1, acc);
      double d2 = xa[4 * r + 2] - (double)v.z; acc = fma(d2, d2, acc);
      double d3 = xa[4 * r + 3] - (double)v.w; acc = fma(d3, d3, acc);
    }
#pragma unroll
    for (int off = 8; off > 0; off >>= 1) acc += __shfl_xor(acc, off, 64);
    if (gl == 0) { sd[sub][q] = acc; sj[sub][q] = j; }
  }
  __syncthreads();
  double dq = (lane < RESC) ? sd[sub][lane] : DBL_MAX;
  int    jq = (lane < RESC) ? sj[sub][lane] : 0x7fffffff;
  int rank = 0;
#pragma unroll
  for (int i = 0; i < RESC; ++i) {
    double di = sd[sub][i]; int ji = sj[sub][i];
    rank += (di < dq || (di == dq && ji < jq)) ? 1 : 0;
  }
  if (lane < RESC && rank < KI) {
    knn[((long)b * NT + n) * KI + rank] = jq;
    atomicAdd(&counts[(long)b * NCTX + jq], 1u);
  }
}

// ---------------- gather-mean: X_edge = (Xn_t + sum_k Xn_c[knn]) / 9 -> bf16 hi/lo ----------------
__global__ __launch_bounds__(256) void k_gather(const float* __restrict__ Xn_t,
                                                const float* __restrict__ Xn_c,
                                                const int* __restrict__ knn,
                                                unsigned short* __restrict__ XeH,
                                                unsigned short* __restrict__ XeL) {
  const int n = blockIdx.x, b = blockIdx.y, c = threadIdx.x;
  const int* kn = knn + ((long)b * NT + n) * KI;
  int j[KI];
#pragma unroll
  for (int q = 0; q < KI; ++q) j[q] = kn[q];
  float acc = Xn_t[((long)b * NT + n) * CH + c];
#pragma unroll
  for (int q = 0; q < KI; ++q) acc += Xn_c[((long)b * NCTX + j[q]) * CH + c];
  float xe = acc / 9.0f;
  long o = ((long)b * NT + n) * CH + c;
  unsigned short h = bf16_rne(xe);
  XeH[o] = h;
  XeL[o] = bf16_rne(xe - __uint_as_float((unsigned)h << 16));
}

// ---------------- fused edge2node GEMM + out_t + scatter-add (X_et never materialized) ----------------
// MFMA: a = WT2 rows (out-ch), b = Xe fragments -> C[ch][node]; epilogue adds bias, stores out_t
// coalesced; then per-node coalesced atomicAdd of S[ch][n] into contrib (replaces k_scatter).
__global__ __launch_bounds__(256) void k_g2f(const unsigned short* __restrict__ XeH_g,
                                             const unsigned short* __restrict__ XeL_g,
                                             const unsigned short* __restrict__ WTh,
                                             const unsigned short* __restrict__ WTl,
                                             const float* __restrict__ bias,
                                             const int* __restrict__ knn,
                                             float* __restrict__ out_t,
                                             float* __restrict__ contrib) {
  __shared__ char smem[34816];   // phase A/B: 2x16KB Xe staging; phase C: float S[256][33]
  __shared__ int knns[256];      // 32 nodes x 8 neighbors
  __bf16* ldsH = (__bf16*)smem;
  __bf16* ldsL = (__bf16*)(smem + 16384);
  const int b = blockIdx.y;
  const int m0 = blockIdx.x * 32;
  const int t = threadIdx.x, w = t >> 6, lane = t & 63;
  const int l31 = lane & 31, lh = lane >> 5;
  const long abase = (long)b * NT * CH;
  const unsigned short* pH = XeH_g + abase + (long)(m0 + l31) * CH;
  const unsigned short* pL = XeL_g + abase + (long)(m0 + l31) * CH;
#pragma unroll
  for (int r = 0; r < 4; ++r) {
    int c = r * 4 + w;
    __builtin_amdgcn_global_load_lds(
        (const __attribute__((address_space(1))) void*)(pH + (c * 2 + lh) * 8),
        (__attribute__((address_space(3))) void*)&ldsH[c * 512], 16, 0, 0);
    __builtin_amdgcn_global_load_lds(
        (const __attribute__((address_space(1))) void*)(pL + (c * 2 + lh) * 8),
        (__attribute__((address_space(3))) void*)&ldsL[c * 512], 16, 0, 0);
  }
  knns[t] = knn[((long)b * NT + m0 + (t >> 3)) * KI + (t & 7)];
  __syncthreads();

  const unsigned short* wh0 = WTh + (long)(w * 64 + l31) * CH;
  const unsigned short* wl0 = WTl + (long)(w * 64 + l31) * CH;
  f32x16 acc0, acc1;
#pragma unroll
  for (int i = 0; i < 16; ++i) { acc0[i] = 0.f; acc1[i] = 0.f; }
#pragma unroll
  for (int s = 0; s < 16; ++s) {
    const int koff = lh * 8 + s * 16;
    bf16x8 beh = *(const bf16x8*)&ldsH[s * 512 + lane * 8];
    bf16x8 bel = *(const bf16x8*)&ldsL[s * 512 + lane * 8];
    bf16x8 ah0 = *(const bf16x8*)(const __bf16*)(wh0 + koff);
    bf16x8 al0 = *(const bf16x8*)(const __bf16*)(wl0 + koff);
    bf16x8 ah1 = *(const bf16x8*)(const __bf16*)(wh0 + 32 * CH + koff);
    bf16x8 al1 = *(const bf16x8*)(const __bf16*)(wl0 + 32 * CH + koff);
    acc0 = __builtin_amdgcn_mfma_f32_32x32x16_bf16(ah0, beh, acc0, 0, 0, 0);
    acc1 = __builtin_amdgcn_mfma_f32_32x32x16_bf16(ah1, beh, acc1, 0, 0, 0);
    acc0 = __builtin_amdgcn_mfma_f32_32x32x16_bf16(al0, beh, acc0, 0, 0, 0);
    acc1 = __builtin_amdgcn_mfma_f32_32x32x16_bf16(al1, beh, acc1, 0, 0, 0);
    acc0 = __builtin_amdgcn_mfma_f32_32x32x16_bf16(ah0, bel, acc0, 0, 0, 0);
    acc1 = __builtin_amdgcn_mfma_f32_32x32x16_bf16(ah1, bel, acc1, 0, 0, 0);
  }
  __syncthreads();   // staging reads done; smem reusable as S

  float* S = (float*)smem;               // [256][33]
  float* ot = out_t + (long)b * CH * NT + m0;
#pragma unroll
  for (int reg = 0; reg < 16; ++reg) {
    const int row = (reg & 3) + 8 * (reg >> 2) + 4 * lh;
    const int ch0 = w * 64 + row, ch1 = ch0 + 32;
    float v0 = acc0[reg] + bias[ch0];
    float v1 = acc1[reg] + bias[ch1];
    S[ch0 * 33 + l31] = v0;
    S[ch1 * 33 + l31] = v1;
    ot[(long)ch0 * NT + l31] = v0;
    ot[(long)ch1 * NT + l31] = v1;
  }
  __syncthreads();

  // scatter: per node nn, all 256 threads = 256 channels, coalesced atomics
  float* cb = contrib + (long)b * NCTX * CH;
#pragma unroll 4
  for (int nn = 0; nn < 32; ++nn) {
    float v = S[t * 33 + nn];
    const int* kn = &knns[nn * 8];
#pragma unroll
    for (int q = 0; q < KI; ++q)
      atomicAdd(&cb[(long)kn[q] * CH + t], v);
  }
}

// ---------------- finalize context outputs: /counts, transpose (128-j tiles, float4 stores) ----------------
__global__ __launch_bounds__(256) void k_fin_c(const float* __restrict__ contrib,
                                               const unsigned* __restrict__ counts,
                                               float* __restrict__ out1,
                                               float* __restrict__ out2) {
  __shared__ float tile[128][33];
  const int b = blockIdx.z;
  const int j0 = blockIdx.x * 128, c0 = blockIdx.y * 32;
  const int tx = threadIdx.x, ty = threadIdx.y;
#pragma unroll
  for (int i = ty; i < 128; i += 8) {
    float cnt = fmaxf((float)counts[(long)b * NCTX + j0 + i], 1.0f);
    tile[i][tx] = contrib[((long)b * NCTX + j0 + i) * CH + c0 + tx] * (1.0f / cnt);
  }
  __syncthreads();
  float* outp = (j0 < NT) ? (out1 + (long)b * CH * NT + j0)
                          : (out2 + (long)b * CH * NT + (j0 - NT));
#pragma unroll
  for (int i = ty; i < 32; i += 8) {
    float4 v;
    v.x = tile[4 * tx + 0][i];
    v.y = tile[4 * tx + 1][i];
    v.z = tile[4 * tx + 2][i];
    v.w = tile[4 * tx + 3][i];
    *(float4*)&outp[(long)(c0 + i) * NT + 4 * tx] = v;
  }
}

extern "C" void kernel_launch(void* const* d_in, const int* in_sizes, int n_in,
                              void* d_out, int out_size, void* d_ws, size_t ws_size,
                              hipStream_t stream) {
  const float* Xt  = (const float*)d_in[0];
  const float* Xc1 = (const float*)d_in[1];
  const float* Xc2 = (const float*)d_in[2];
  const float* W1  = (const float*)d_in[3];
  const float* b1  = (const float*)d_in[4];
  const float* W2  = (const float*)d_in[5];
  const float* b2  = (const float*)d_in[6];
  float* out = (float*)d_out;

  // common ws layout (68.42 MB)
  float* P = (float*)d_ws;                               // XcT -> (fallback Xn_c) -> contrib
  float* Q = P + (long)BATCH * NCTX * CH;                // XtT -> XeH/XeL
  float* R = Q + (long)BATCH * NT * CH;                  // (fallback cand) -> Xn_t
  float* nrm = R + (long)BATCH * NT * CH;
  unsigned* counts = (unsigned*)(nrm + (long)BATCH * NCTX);
  int* knn = (int*)(counts + (long)BATCH * NCTX);
  unsigned short* WT1h = (unsigned short*)(knn + (long)BATCH * NT * KI);
  unsigned short* WT1l = WT1h + CH * CH;
  unsigned short* WT2h = WT1l + CH * CH;
  unsigned short* WT2l = WT2h + CH * CH;
  // fat-mode extras: separate Xn_c (33.55 MB) + cand (5.24 MB)
  float* Xn_c_fat = (float*)(WT2l + CH * CH);
  unsigned* cand_fat = (unsigned*)(Xn_c_fat + (long)BATCH * NCTX * CH);
  const size_t need_fat = (size_t)((char*)(cand_fat + (long)BATCH * NT * NKEY) - (char*)d_ws);
  const bool fat = ws_size >= need_fat;

  unsigned* cand = fat ? cand_fat : (unsigned*)R;
  float* Xn_c = fat ? Xn_c_fat : P;
  float* Xn_t = R;

  unsigned short* XcBh = (unsigned short*)d_out;
  unsigned short* XtBh = XcBh + (long)BATCH * NCTX * CH;
  unsigned short* XcBl = XtBh + (long)BATCH * NT * CH;
  unsigned short* XtBl = XcBl + (long)BATCH * NCTX * CH;

  unsigned short* XeH = (unsigned short*)Q;   // after rescore, Q (XtT) is dead
  unsigned short* XeL = XeH + (long)BATCH * NT * CH;

  float* out_t  = out;             // overwrites dead XcBh region
  float* out_c1 = out + (long)BATCH * CH * NT;
  float* out_c2 = out + 2L * BATCH * CH * NT;

  dim3 tb(32, 8);

  hipMemsetAsync(nrm, 0, (size_t)BATCH * NCTX * 8, stream);   // nrm + counts

  k_prep<<<dim3(3072 + 128), tb, 0, stream>>>(Xt, Xc1, Xc2, Q, P, XtBh, XtBl, XcBh, XcBl, nrm,
                                              W1, W2, WT1h, WT1l, WT2h, WT2l);

  if (fat) {
    // dist + both node2edge GEMMs, role-interleaved for co-residency
    k_main<<<dim3(2560), 256, 0, stream>>>(
        (const __bf16*)XcBh, (const __bf16*)XtBh, nrm, cand,
        XtBh, XtBl, XcBh, XcBl, WT1h, WT1l, b1, Xn_t, Xn_c, 1);
    k_rescore<<<dim3(NT / 4, BATCH), 256, 0, stream>>>(Q, P, cand, knn, counts);
  } else {
    k_main<<<dim3(1024), 256, 0, stream>>>(
        (const __bf16*)XcBh, (const __bf16*)XtBh, nrm, cand,
        XtBh, XtBl, XcBh, XcBl, WT1h, WT1l, b1, Xn_t, Xn_c, 0);
    k_rescore<<<dim3(NT / 4, BATCH), 256, 0, stream>>>(Q, P, cand, knn, counts);
    k_gemm_mfma<<<dim3(NT / 32, BATCH), 256, 0, stream>>>(XtBh, XtBl, WT1h, WT1l, b1, Xn_t, NT);
    k_gemm_mfma<<<dim3(NCTX / 32, BATCH), 256, 0, stream>>>(XcBh, XcBl, WT1h, WT1l, b1, Xn_c, NCTX);
  }

  // edge mean-pool -> Q as bf16 hi/lo
  k_gather<<<dim3(NT, BATCH), 256, 0, stream>>>(Xn_t, Xn_c, knn, XeH, XeL);

  // P dead now -> contrib
  hipMemsetAsync(P, 0, (size_t)BATCH * NCTX * CH * 4, stream);

  // fused edge2node + out_t + scatter atomics
  k_g2f<<<dim3(NT / 32, BATCH), 256, 0, stream>>>(XeH, XeL, WT2h, WT2l, b2, knn, out_t, P);

  k_fin_c<<<dim3(NCTX / 128, CH / 32, BATCH), tb, 0, stream>>>(P, counts, out_c1, out_c2);
}

// Round 14
// 392.341 us; speedup vs baseline: 1.1197x; 1.1197x over previous
//
#include <hip/hip_runtime.h>
#include <math.h>
#include <float.h>

#define BATCH 4
#define CH    256
#define NT    4096
#define NCTX  8192
#define KI    8

// coarse-selection geometry
#define CSEL    10                 // per-split top-C after lane-half merge (>=8+2 slack => safe)
#define DNSPLIT 8                  // ctx splits
#define CTX_PER (NCTX / DNSPLIT)   // 1024
#define NTILE   (CTX_PER / 32)     // 32 tiles of 32 ctx
#define NKEY    (DNSPLIT * CSEL)   // 80 packed keys per target
#define RESC    12                 // keys kept for exact fp64 rescore

typedef __attribute__((ext_vector_type(8)))  __bf16 bf16x8;
typedef __attribute__((ext_vector_type(16))) float  f32x16;

__device__ __forceinline__ unsigned short bf16_rne(float v) {
  unsigned u = __float_as_uint(v);
  return (unsigned short)((u + 0x7fffu + ((u >> 16) & 1u)) >> 16);
}

// ---------------- prep: transpose (128-ch tiles, wide stores) + W transpose, role-fused ----------------
__global__ __launch_bounds__(256) void k_prep(const float* __restrict__ Xt,
                                              const float* __restrict__ Xc1,
                                              const float* __restrict__ Xc2,
                                              float* __restrict__ Q,
                                              float* __restrict__ P,
                                              unsigned short* __restrict__ XtBh,
                                              unsigned short* __restrict__ XtBl,
                                              unsigned short* __restrict__ XcBh,
                                              unsigned short* __restrict__ XcBl,
                                              float* __restrict__ nrm,
                                              const float* __restrict__ W1,
                                              const float* __restrict__ W2,
                                              unsigned short* __restrict__ WT1h,
                                              unsigned short* __restrict__ WT1l,
                                              unsigned short* __restrict__ WT2h,
                                              unsigned short* __restrict__ WT2l) {
  __shared__ float tile[128][33];   // 16.9 KB
  __shared__ float ps[8][32];
  const int bid = blockIdx.x;
  const int tx = threadIdx.x, ty = threadIdx.y;

  if (bid < 3072) {
    const int x = bid & 127, y = (bid >> 7) & 1, z = bid >> 8;
    const int which = z >> 2, b = z & 3;
    const float* src;
    float* dF; unsigned short *dH, *dL; float* nrmp = nullptr;
    if (which == 0) {
      src = Xt + (long)b * CH * NT;
      dF = Q + (long)b * NT * CH;
      dH = XtBh + (long)b * NT * CH;  dL = XtBl + (long)b * NT * CH;
    } else if (which == 1) {
      src = Xc1 + (long)b * CH * NT;
      dF = P + (long)b * NCTX * CH;
      dH = XcBh + (long)b * NCTX * CH;  dL = XcBl + (long)b * NCTX * CH;
      nrmp = nrm + (long)b * NCTX;
    } else {
      src = Xc2 + (long)b * CH * NT;
      dF = P + ((long)b * NCTX + NT) * CH;
      dH = XcBh + ((long)b * NCTX + NT) * CH;  dL = XcBl + ((long)b * NCTX + NT) * CH;
      nrmp = nrm + (long)b * NCTX + NT;
    }
    const int m0 = x * 32, c0 = y * 128;
    float part = 0.f;
#pragma unroll
    for (int i = ty; i < 128; i += 8) {
      float v = src[(long)(c0 + i) * NT + (m0 + tx)];
      tile[i][tx] = v;
      part = fmaf(v, v, part);
    }
    if (which) ps[ty][tx] = part;
    __syncthreads();
#pragma unroll
    for (int i = ty; i < 32; i += 8) {
      float v0 = tile[4 * tx + 0][i];
      float v1 = tile[4 * tx + 1][i];
      float v2 = tile[4 * tx + 2][i];
      float v3 = tile[4 * tx + 3][i];
      long o = (long)(m0 + i) * CH + (c0 + 4 * tx);
      float4 f4; f4.x = v0; f4.y = v1; f4.z = v2; f4.w = v3;
      *(float4*)&dF[o] = f4;
      unsigned short h0 = bf16_rne(v0), h1 = bf16_rne(v1), h2 = bf16_rne(v2), h3 = bf16_rne(v3);
      ushort4 h4; h4.x = h0; h4.y = h1; h4.z = h2; h4.w = h3;
      *(ushort4*)&dH[o] = h4;
      ushort4 l4;
      l4.x = bf16_rne(v0 - __uint_as_float((unsigned)h0 << 16));
      l4.y = bf16_rne(v1 - __uint_as_float((unsigned)h1 << 16));
      l4.z = bf16_rne(v2 - __uint_as_float((unsigned)h2 << 16));
      l4.w = bf16_rne(v3 - __uint_as_float((unsigned)h3 << 16));
      *(ushort4*)&dL[o] = l4;
    }
    if (which && ty == 0) {
      float s = 0.f;
#pragma unroll
      for (int j = 0; j < 8; ++j) s += ps[j][tx];
      atomicAdd(&nrmp[m0 + tx], -0.5f * s);
    }
  } else {
    const int r = bid - 3072;
    const int n0 = (r & 7) * 32, k0 = ((r >> 3) & 7) * 32;
    const float* W = (r >> 6) ? W2 : W1;
    unsigned short* WTh = (r >> 6) ? WT2h : WT1h;
    unsigned short* WTl = (r >> 6) ? WT2l : WT1l;
#pragma unroll
    for (int i = ty; i < 32; i += 8)
      tile[i][tx] = W[(k0 + i) * CH + (n0 + tx)];
    __syncthreads();
#pragma unroll
    for (int i = ty; i < 32; i += 8) {
      float v = tile[tx][i];
      int o = (n0 + i) * CH + (k0 + tx);
      unsigned short h = bf16_rne(v);
      WTh[o] = h;
      WTl[o] = bf16_rne(v - __uint_as_float((unsigned)h << 16));
    }
  }
}

// ---------------- main: dist (bid<1024, XCD-correct lid=bid) then gemm (bid>=1024, fat only) ----------------
// Sequential role layout (R12-proven): gemm blocks queue behind dist and backfill CUs as dist
// blocks drain. Interleaving regressed (R13): broke XCD locality + displaced dist issue slots.
__global__ __launch_bounds__(256) void k_main(const __bf16* __restrict__ XcB,
                                              const __bf16* __restrict__ XtB,
                                              const float* __restrict__ nrm,
                                              unsigned* __restrict__ cand,
                                              const unsigned short* __restrict__ XtBh,
                                              const unsigned short* __restrict__ XtBl,
                                              const unsigned short* __restrict__ XcBh,
                                              const unsigned short* __restrict__ XcBl,
                                              const unsigned short* __restrict__ WTh,
                                              const unsigned short* __restrict__ WTl,
                                              const float* __restrict__ bias,
                                              float* __restrict__ outT,
                                              float* __restrict__ outC) {
  __shared__ __bf16 lds[2][32 * CH];   // 32 KB, shared by both roles
  const int bid = blockIdx.x;
  const int t = threadIdx.x, w = t >> 6, lane = t & 63;
  const int l31 = lane & 31, lh = lane >> 5;

  if (bid < 1024) {
    // ---- dist role ----
    const int lid = bid;
    const int xk = lid & 7;
    const int b = xk >> 1, jh = xk & 1;
    const int jw = (lid >> 3) & 15, split = lid >> 7;
    const int tgt0 = (jh * 16 + jw) * 128 + w * 32;
    const int cbase = split * CTX_PER;
    const float* nrmt = nrm + (long)b * NCTX + cbase;

    const __bf16* tp = XtB + ((long)b * NT + tgt0 + l31) * CH + lh * 8;
    bf16x8 bfrag[16];
#pragma unroll
    for (int s = 0; s < 16; ++s) bfrag[s] = *(const bf16x8*)(tp + s * 16);

    unsigned kd[CSEL];
#pragma unroll
    for (int q = 0; q < CSEL; ++q) kd[q] = 0xFFFFFFFFu;

    const __bf16* cp = XcB + ((long)b * NCTX + cbase + l31) * CH;

    auto STAGE = [&](int buf, int jt) {
#pragma unroll
      for (int r = 0; r < 4; ++r) {
        int c = r * 4 + w;
        const __bf16* src = cp + (long)jt * 32 * CH + (c * 2 + lh) * 8;
        __bf16* dst = &lds[buf][c * 512];
        __builtin_amdgcn_global_load_lds((const __attribute__((address_space(1))) void*)src,
                                         (__attribute__((address_space(3))) void*)dst,
                                         16, 0, 0);
      }
    };

    STAGE(0, 0);
    __syncthreads();

    int cur = 0;
    for (int jt = 0; jt < NTILE; ++jt) {
      if (jt + 1 < NTILE) STAGE(cur ^ 1, jt + 1);

      const int ct0 = jt * 32;
      f32x16 acc;
#pragma unroll
      for (int g = 0; g < 4; ++g) {
        float4 nv = *(const float4*)&nrmt[ct0 + 8 * g + 4 * lh];
        acc[4 * g + 0] = nv.x; acc[4 * g + 1] = nv.y;
        acc[4 * g + 2] = nv.z; acc[4 * g + 3] = nv.w;
      }
#pragma unroll
      for (int s = 0; s < 16; ++s) {
        bf16x8 a = *(const bf16x8*)(&lds[cur][s * 512 + lane * 8]);
        acc = __builtin_amdgcn_mfma_f32_32x32x16_bf16(a, bfrag[s], acc, 0, 0, 0);
      }

#pragma unroll
      for (int reg = 0; reg < 16; ++reg) {
        const int row = (reg & 3) + 8 * (reg >> 2) + lh * 4;
        float sc = fmaf(acc[reg], -2.0f, 512.0f);
        unsigned key = (__float_as_uint(sc) & 0xFFFFF800u) | (unsigned)ct0 | (unsigned)row;
#pragma unroll
        for (int q = 0; q < CSEL; ++q) {
          unsigned lo = min(key, kd[q]);
          key = max(key, kd[q]);
          kd[q] = lo;
        }
      }
      __syncthreads();
      cur ^= 1;
    }

    unsigned oth[CSEL];
#pragma unroll
    for (int q = 0; q < CSEL; ++q) oth[q] = (unsigned)__shfl_xor((int)kd[q], 32, 64);
    if (lh == 0) {
      long ob = (((long)b * NT + tgt0 + l31) * DNSPLIT + split) * CSEL;
#pragma unroll
      for (int q = 0; q < CSEL; ++q)
        cand[ob + q] = min(kd[q], oth[CSEL - 1 - q]);
    }
  } else {
    // ---- gemm role (fat mode only) ----
    int g = bid - 1024;
    const unsigned short *Ah, *Al; float* out; int M, m0, b;
    if (g < 512) { Ah = XtBh; Al = XtBl; out = outT; M = NT;   m0 = (g & 127) * 32; b = g >> 7; }
    else { g -= 512; Ah = XcBh; Al = XcBl; out = outC; M = NCTX; m0 = (g & 255) * 32; b = g >> 8; }
    __bf16* ldsH = lds[0];
    __bf16* ldsL = lds[1];
    const long abase = (long)b * M * CH;
    const unsigned short* pH = Ah + abase + (long)(m0 + l31) * CH;
    const unsigned short* pL = Al + abase + (long)(m0 + l31) * CH;
#pragma unroll
    for (int r = 0; r < 4; ++r) {
      int c = r * 4 + w;
      __builtin_amdgcn_global_load_lds(
          (const __attribute__((address_space(1))) void*)(pH + (c * 2 + lh) * 8),
          (__attribute__((address_space(3))) void*)&ldsH[c * 512], 16, 0, 0);
      __builtin_amdgcn_global_load_lds(
          (const __attribute__((address_space(1))) void*)(pL + (c * 2 + lh) * 8),
          (__attribute__((address_space(3))) void*)&ldsL[c * 512], 16, 0, 0);
    }
    __syncthreads();

    const int n0 = w * 64;
    f32x16 acc0, acc1;
#pragma unroll
    for (int i = 0; i < 16; ++i) { acc0[i] = 0.f; acc1[i] = 0.f; }
#pragma unroll
    for (int s = 0; s < 16; ++s) {
      bf16x8 ah = *(const bf16x8*)&ldsH[s * 512 + lane * 8];
      bf16x8 al = *(const bf16x8*)&ldsL[s * 512 + lane * 8];
      const int koff = lh * 8 + s * 16;
      bf16x8 bh0 = *(const bf16x8*)&WTh[(n0 + l31) * CH + koff];
      bf16x8 bl0 = *(const bf16x8*)&WTl[(n0 + l31) * CH + koff];
      bf16x8 bh1 = *(const bf16x8*)&WTh[(n0 + 32 + l31) * CH + koff];
      bf16x8 bl1 = *(const bf16x8*)&WTl[(n0 + 32 + l31) * CH + koff];
      acc0 = __builtin_amdgcn_mfma_f32_32x32x16_bf16(ah, bh0, acc0, 0, 0, 0);
      acc1 = __builtin_amdgcn_mfma_f32_32x32x16_bf16(ah, bh1, acc1, 0, 0, 0);
      acc0 = __builtin_amdgcn_mfma_f32_32x32x16_bf16(ah, bl0, acc0, 0, 0, 0);
      acc1 = __builtin_amdgcn_mfma_f32_32x32x16_bf16(ah, bl1, acc1, 0, 0, 0);
      acc0 = __builtin_amdgcn_mfma_f32_32x32x16_bf16(al, bh0, acc0, 0, 0, 0);
      acc1 = __builtin_amdgcn_mfma_f32_32x32x16_bf16(al, bh1, acc1, 0, 0, 0);
    }
    float* ob = out + abase;
    float bi0 = bias[n0 + l31], bi1 = bias[n0 + 32 + l31];
#pragma unroll
    for (int reg = 0; reg < 16; ++reg) {
      int row = (reg & 3) + 8 * (reg >> 2) + 4 * lh;
      ob[(long)(m0 + row) * CH + n0 + l31]      = acc0[reg] + bi0;
      ob[(long)(m0 + row) * CH + n0 + 32 + l31] = acc1[reg] + bi1;
    }
  }
}

// ---------------- standalone node2edge GEMM (fallback mode) ----------------
__global__ __launch_bounds__(256) void k_gemm_mfma(const unsigned short* __restrict__ Ah,
                                                   const unsigned short* __restrict__ Al,
                                                   const unsigned short* __restrict__ WTh,
                                                   const unsigned short* __restrict__ WTl,
                                                   const float* __restrict__ bias,
                                                   float* __restrict__ out, int M) {
  __shared__ __bf16 ldsH[32 * CH];
  __shared__ __bf16 ldsL[32 * CH];
  const int b = blockIdx.y;
  const int m0 = blockIdx.x * 32;
  const int t = threadIdx.x, w = t >> 6, lane = t & 63;
  const int l31 = lane & 31, lh = lane >> 5;
  const long abase = (long)b * M * CH;
  const unsigned short* pH = Ah + abase + (long)(m0 + l31) * CH;
  const unsigned short* pL = Al + abase + (long)(m0 + l31) * CH;
#pragma unroll
  for (int r = 0; r < 4; ++r) {
    int c = r * 4 + w;
    __builtin_amdgcn_global_load_lds(
        (const __attribute__((address_space(1))) void*)(pH + (c * 2 + lh) * 8),
        (__attribute__((address_space(3))) void*)&ldsH[c * 512], 16, 0, 0);
    __builtin_amdgcn_global_load_lds(
        (const __attribute__((address_space(1))) void*)(pL + (c * 2 + lh) * 8),
        (__attribute__((address_space(3))) void*)&ldsL[c * 512], 16, 0, 0);
  }
  __syncthreads();

  const int n0 = w * 64;
  f32x16 acc0, acc1;
#pragma unroll
  for (int i = 0; i < 16; ++i) { acc0[i] = 0.f; acc1[i] = 0.f; }
#pragma unroll
  for (int s = 0; s < 16; ++s) {
    bf16x8 ah = *(const bf16x8*)&ldsH[s * 512 + lane * 8];
    bf16x8 al = *(const bf16x8*)&ldsL[s * 512 + lane * 8];
    const int koff = lh * 8 + s * 16;
    bf16x8 bh0 = *(const bf16x8*)&WTh[(n0 + l31) * CH + koff];
    bf16x8 bl0 = *(const bf16x8*)&WTl[(n0 + l31) * CH + koff];
    bf16x8 bh1 = *(const bf16x8*)&WTh[(n0 + 32 + l31) * CH + koff];
    bf16x8 bl1 = *(const bf16x8*)&WTl[(n0 + 32 + l31) * CH + koff];
    acc0 = __builtin_amdgcn_mfma_f32_32x32x16_bf16(ah, bh0, acc0, 0, 0, 0);
    acc1 = __builtin_amdgcn_mfma_f32_32x32x16_bf16(ah, bh1, acc1, 0, 0, 0);
    acc0 = __builtin_amdgcn_mfma_f32_32x32x16_bf16(ah, bl0, acc0, 0, 0, 0);
    acc1 = __builtin_amdgcn_mfma_f32_32x32x16_bf16(ah, bl1, acc1, 0, 0, 0);
    acc0 = __builtin_amdgcn_mfma_f32_32x32x16_bf16(al, bh0, acc0, 0, 0, 0);
    acc1 = __builtin_amdgcn_mfma_f32_32x32x16_bf16(al, bh1, acc1, 0, 0, 0);
  }
  float* ob = out + abase;
  float bi0 = bias[n0 + l31], bi1 = bias[n0 + 32 + l31];
#pragma unroll
  for (int reg = 0; reg < 16; ++reg) {
    int row = (reg & 3) + 8 * (reg >> 2) + 4 * lh;
    ob[(long)(m0 + row) * CH + n0 + l31]      = acc0[reg] + bi0;
    ob[(long)(m0 + row) * CH + n0 + 32 + l31] = acc1[reg] + bi1;
  }
}

// ---------------- rescore: 4 targets/block, coarse top-RESC of 80 keys, fp64 exact, rank-8 + counts ----------------
__global__ __launch_bounds__(256) void k_rescore(const float* __restrict__ XtT,
                                                 const float* __restrict__ XcT,
                                                 const unsigned* __restrict__ cand,
                                                 int* __restrict__ knn,
                                                 unsigned* __restrict__ counts) {
  const int t = threadIdx.x, sub = t >> 6, lane = t & 63;
  const int n = blockIdx.x * 4 + sub, b = blockIdx.y;
  const int grp = lane >> 4, gl = lane & 15;
  __shared__ unsigned sk[4][NKEY];
  __shared__ int cidx[4][RESC];
  __shared__ double sd[4][RESC];
  __shared__ int sj[4][RESC];
  const unsigned* kp = cand + ((long)b * NT + n) * NKEY;
  unsigned k0 = kp[lane];
  unsigned k1 = (lane < NKEY - 64) ? kp[64 + lane] : 0xFFFFFFFFu;
  sk[sub][lane] = k0;
  if (lane < NKEY - 64) sk[sub][64 + lane] = k1;
  __syncthreads();
  int r0 = 0, r1 = 0;
  for (int i = 0; i < NKEY; ++i) {
    unsigned s = sk[sub][i];
    r0 += (s < k0 || (s == k0 && i < lane)) ? 1 : 0;
    r1 += (s < k1 || (s == k1 && i < 64 + lane)) ? 1 : 0;
  }
  if (r0 < RESC) cidx[sub][r0] = (lane / CSEL) * CTX_PER + (int)(k0 & 0x7FFu);
  if (lane < NKEY - 64 && r1 < RESC)
    cidx[sub][r1] = ((64 + lane) / CSEL) * CTX_PER + (int)(k1 & 0x7FFu);
  __syncthreads();

  const float* xt = XtT + ((long)b * NT + n) * CH + gl * 16;
  double xa[16];
#pragma unroll
  for (int r = 0; r < 4; ++r) {
    float4 v = *(const float4*)(xt + r * 4);
    xa[4 * r + 0] = (double)v.x; xa[4 * r + 1] = (double)v.y;
    xa[4 * r + 2] = (double)v.z; xa[4 * r + 3] = (double)v.w;
  }
#pragma unroll
  for (int q0 = 0; q0 < RESC; q0 += 4) {
    int q = q0 + grp;
    int j = cidx[sub][q];
    const float* xc = XcT + ((long)b * NCTX + j) * CH + gl * 16;
    double acc = 0.0;
#pragma unroll
    for (int r = 0; r < 4; ++r) {
      float4 v = *(const float4*)(xc + r * 4);
      double d0 = xa[4 * r + 0] - (double)v.x; acc = fma(d0, d0, acc);
      double d1 = xa[4 * r + 1] - (double)v.y; acc = fma(d1, d1, acc);
      double d2 = xa[4 * r + 2] - (double)v.z; acc = fma(d2, d2, acc);
      double d3 = xa[4 * r + 3] - (double)v.w; acc = fma(d3, d3, acc);
    }
#pragma unroll
    for (int off = 8; off > 0; off >>= 1) acc += __shfl_xor(acc, off, 64);
    if (gl == 0) { sd[sub][q] = acc; sj[sub][q] = j; }
  }
  __syncthreads();
  double dq = (lane < RESC) ? sd[sub][lane] : DBL_MAX;
  int    jq = (lane < RESC) ? sj[sub][lane] : 0x7fffffff;
  int rank = 0;
#pragma unroll
  for (int i = 0; i < RESC; ++i) {
    double di = sd[sub][i]; int ji = sj[sub][i];
    rank += (di < dq || (di == dq && ji < jq)) ? 1 : 0;
  }
  if (lane < RESC && rank < KI) {
    knn[((long)b * NT + n) * KI + rank] = jq;
    atomicAdd(&counts[(long)b * NCTX + jq], 1u);
  }
}

// ---------------- gather-mean: X_edge = (Xn_t + sum_k Xn_c[knn]) / 9 -> bf16 hi/lo ----------------
__global__ __launch_bounds__(256) void k_gather(const float* __restrict__ Xn_t,
                                                const float* __restrict__ Xn_c,
                                                const int* __restrict__ knn,
                                                unsigned short* __restrict__ XeH,
                                                unsigned short* __restrict__ XeL) {
  const int n = blockIdx.x, b = blockIdx.y, c = threadIdx.x;
  const int* kn = knn + ((long)b * NT + n) * KI;
  int j[KI];
#pragma unroll
  for (int q = 0; q < KI; ++q) j[q] = kn[q];
  float acc = Xn_t[((long)b * NT + n) * CH + c];
#pragma unroll
  for (int q = 0; q < KI; ++q) acc += Xn_c[((long)b * NCTX + j[q]) * CH + c];
  float xe = acc / 9.0f;
  long o = ((long)b * NT + n) * CH + c;
  unsigned short h = bf16_rne(xe);
  XeH[o] = h;
  XeL[o] = bf16_rne(xe - __uint_as_float((unsigned)h << 16));
}

// ---------------- fused edge2node GEMM + out_t + scatter-add (X_et never materialized) ----------------
__global__ __launch_bounds__(256) void k_g2f(const unsigned short* __restrict__ XeH_g,
                                             const unsigned short* __restrict__ XeL_g,
                                             const unsigned short* __restrict__ WTh,
                                             const unsigned short* __restrict__ WTl,
                                             const float* __restrict__ bias,
                                             const int* __restrict__ knn,
                                             float* __restrict__ out_t,
                                             float* __restrict__ contrib) {
  __shared__ char smem[34816];   // phase A/B: 2x16KB Xe staging; phase C: float S[256][33]
  __shared__ int knns[256];      // 32 nodes x 8 neighbors
  __bf16* ldsH = (__bf16*)smem;
  __bf16* ldsL = (__bf16*)(smem + 16384);
  const int b = blockIdx.y;
  const int m0 = blockIdx.x * 32;
  const int t = threadIdx.x, w = t >> 6, lane = t & 63;
  const int l31 = lane & 31, lh = lane >> 5;
  const long abase = (long)b * NT * CH;
  const unsigned short* pH = XeH_g + abase + (long)(m0 + l31) * CH;
  const unsigned short* pL = XeL_g + abase + (long)(m0 + l31) * CH;
#pragma unroll
  for (int r = 0; r < 4; ++r) {
    int c = r * 4 + w;
    __builtin_amdgcn_global_load_lds(
        (const __attribute__((address_space(1))) void*)(pH + (c * 2 + lh) * 8),
        (__attribute__((address_space(3))) void*)&ldsH[c * 512], 16, 0, 0);
    __builtin_amdgcn_global_load_lds(
        (const __attribute__((address_space(1))) void*)(pL + (c * 2 + lh) * 8),
        (__attribute__((address_space(3))) void*)&ldsL[c * 512], 16, 0, 0);
  }
  knns[t] = knn[((long)b * NT + m0 + (t >> 3)) * KI + (t & 7)];
  __syncthreads();

  const unsigned short* wh0 = WTh + (long)(w * 64 + l31) * CH;
  const unsigned short* wl0 = WTl + (long)(w * 64 + l31) * CH;
  f32x16 acc0, acc1;
#pragma unroll
  for (int i = 0; i < 16; ++i) { acc0[i] = 0.f; acc1[i] = 0.f; }
#pragma unroll
  for (int s = 0; s < 16; ++s) {
    const int koff = lh * 8 + s * 16;
    bf16x8 beh = *(const bf16x8*)&ldsH[s * 512 + lane * 8];
    bf16x8 bel = *(const bf16x8*)&ldsL[s * 512 + lane * 8];
    bf16x8 ah0 = *(const bf16x8*)(const __bf16*)(wh0 + koff);
    bf16x8 al0 = *(const bf16x8*)(const __bf16*)(wl0 + koff);
    bf16x8 ah1 = *(const bf16x8*)(const __bf16*)(wh0 + 32 * CH + koff);
    bf16x8 al1 = *(const bf16x8*)(const __bf16*)(wl0 + 32 * CH + koff);
    acc0 = __builtin_amdgcn_mfma_f32_32x32x16_bf16(ah0, beh, acc0, 0, 0, 0);
    acc1 = __builtin_amdgcn_mfma_f32_32x32x16_bf16(ah1, beh, acc1, 0, 0, 0);
    acc0 = __builtin_amdgcn_mfma_f32_32x32x16_bf16(al0, beh, acc0, 0, 0, 0);
    acc1 = __builtin_amdgcn_mfma_f32_32x32x16_bf16(al1, beh, acc1, 0, 0, 0);
    acc0 = __builtin_amdgcn_mfma_f32_32x32x16_bf16(ah0, bel, acc0, 0, 0, 0);
    acc1 = __builtin_amdgcn_mfma_f32_32x32x16_bf16(ah1, bel, acc1, 0, 0, 0);
  }
  __syncthreads();   // staging reads done; smem reusable as S

  float* S = (float*)smem;               // [256][33]
  float* ot = out_t + (long)b * CH * NT + m0;
#pragma unroll
  for (int reg = 0; reg < 16; ++reg) {
    const int row = (reg & 3) + 8 * (reg >> 2) + 4 * lh;
    const int ch0 = w * 64 + row, ch1 = ch0 + 32;
    float v0 = acc0[reg] + bias[ch0];
    float v1 = acc1[reg] + bias[ch1];
    S[ch0 * 33 + l31] = v0;
    S[ch1 * 33 + l31] = v1;
    ot[(long)ch0 * NT + l31] = v0;
    ot[(long)ch1 * NT + l31] = v1;
  }
  __syncthreads();

  // scatter: per node nn, all 256 threads = 256 channels, coalesced atomics
  float* cb = contrib + (long)b * NCTX * CH;
#pragma unroll 4
  for (int nn = 0; nn < 32; ++nn) {
    float v = S[t * 33 + nn];
    const int* kn = &knns[nn * 8];
#pragma unroll
    for (int q = 0; q < KI; ++q)
      atomicAdd(&cb[(long)kn[q] * CH + t], v);
  }
}

// ---------------- finalize context outputs: /counts, transpose (128-j tiles, float4 stores) ----------------
__global__ __launch_bounds__(256) void k_fin_c(const float* __restrict__ contrib,
                                               const unsigned* __restrict__ counts,
                                               float* __restrict__ out1,
                                               float* __restrict__ out2) {
  __shared__ float tile[128][33];
  const int b = blockIdx.z;
  const int j0 = blockIdx.x * 128, c0 = blockIdx.y * 32;
  const int tx = threadIdx.x, ty = threadIdx.y;
#pragma unroll
  for (int i = ty; i < 128; i += 8) {
    float cnt = fmaxf((float)counts[(long)b * NCTX + j0 + i], 1.0f);
    tile[i][tx] = contrib[((long)b * NCTX + j0 + i) * CH + c0 + tx] * (1.0f / cnt);
  }
  __syncthreads();
  float* outp = (j0 < NT) ? (out1 + (long)b * CH * NT + j0)
                          : (out2 + (long)b * CH * NT + (j0 - NT));
#pragma unroll
  for (int i = ty; i < 32; i += 8) {
    float4 v;
    v.x = tile[4 * tx + 0][i];
    v.y = tile[4 * tx + 1][i];
    v.z = tile[4 * tx + 2][i];
    v.w = tile[4 * tx + 3][i];
    *(float4*)&outp[(long)(c0 + i) * NT + 4 * tx] = v;
  }
}

extern "C" void kernel_launch(void* const* d_in, const int* in_sizes, int n_in,
                              void* d_out, int out_size, void* d_ws, size_t ws_size,
                              hipStream_t stream) {
  const float* Xt  = (const float*)d_in[0];
  const float* Xc1 = (const float*)d_in[1];
  const float* Xc2 = (const float*)d_in[2];
  const float* W1  = (const float*)d_in[3];
  const float* b1  = (const float*)d_in[4];
  const float* W2  = (const float*)d_in[5];
  const float* b2  = (const float*)d_in[6];
  float* out = (float*)d_out;

  // common ws layout (68.42 MB)
  float* P = (float*)d_ws;                               // XcT -> (fallback Xn_c) -> contrib
  float* Q = P + (long)BATCH * NCTX * CH;                // XtT -> XeH/XeL
  float* R = Q + (long)BATCH * NT * CH;                  // (fallback cand) -> Xn_t
  float* nrm = R + (long)BATCH * NT * CH;
  unsigned* counts = (unsigned*)(nrm + (long)BATCH * NCTX);
  int* knn = (int*)(counts + (long)BATCH * NCTX);
  unsigned short* WT1h = (unsigned short*)(knn + (long)BATCH * NT * KI);
  unsigned short* WT1l = WT1h + CH * CH;
  unsigned short* WT2h = WT1l + CH * CH;
  unsigned short* WT2l = WT2h + CH * CH;
  // fat-mode extras: separate Xn_c (33.55 MB) + cand (5.24 MB)
  float* Xn_c_fat = (float*)(WT2l + CH * CH);
  unsigned* cand_fat = (unsigned*)(Xn_c_fat + (long)BATCH * NCTX * CH);
  const size_t need_fat = (size_t)((char*)(cand_fat + (long)BATCH * NT * NKEY) - (char*)d_ws);
  const bool fat = ws_size >= need_fat;

  unsigned* cand = fat ? cand_fat : (unsigned*)R;
  float* Xn_c = fat ? Xn_c_fat : P;
  float* Xn_t = R;

  unsigned short* XcBh = (unsigned short*)d_out;
  unsigned short* XtBh = XcBh + (long)BATCH * NCTX * CH;
  unsigned short* XcBl = XtBh + (long)BATCH * NT * CH;
  unsigned short* XtBl = XcBl + (long)BATCH * NCTX * CH;

  unsigned short* XeH = (unsigned short*)Q;   // after rescore, Q (XtT) is dead
  unsigned short* XeL = XeH + (long)BATCH * NT * CH;

  float* out_t  = out;             // overwrites dead XcBh region
  float* out_c1 = out + (long)BATCH * CH * NT;
  float* out_c2 = out + 2L * BATCH * CH * NT;

  dim3 tb(32, 8);

  hipMemsetAsync(nrm, 0, (size_t)BATCH * NCTX * 8, stream);   // nrm + counts

  k_prep<<<dim3(3072 + 128), tb, 0, stream>>>(Xt, Xc1, Xc2, Q, P, XtBh, XtBl, XcBh, XcBl, nrm,
                                              W1, W2, WT1h, WT1l, WT2h, WT2l);

  if (fat) {
    // dist (XCD-correct bids 0..1023) + both node2edge GEMMs queued behind (R12-proven layout)
    k_main<<<dim3(1024 + 512 + 1024), 256, 0, stream>>>(
        (const __bf16*)XcBh, (const __bf16*)XtBh, nrm, cand,
        XtBh, XtBl, XcBh, XcBl, WT1h, WT1l, b1, Xn_t, Xn_c);
    k_rescore<<<dim3(NT / 4, BATCH), 256, 0, stream>>>(Q, P, cand, knn, counts);
  } else {
    k_main<<<dim3(1024), 256, 0, stream>>>(
        (const __bf16*)XcBh, (const __bf16*)XtBh, nrm, cand,
        XtBh, XtBl, XcBh, XcBl, WT1h, WT1l, b1, Xn_t, Xn_c);
    k_rescore<<<dim3(NT / 4, BATCH), 256, 0, stream>>>(Q, P, cand, knn, counts);
    k_gemm_mfma<<<dim3(NT / 32, BATCH), 256, 0, stream>>>(XtBh, XtBl, WT1h, WT1l, b1, Xn_t, NT);
    k_gemm_mfma<<<dim3(NCTX / 32, BATCH), 256, 0, stream>>>(XcBh, XcBl, WT1h, WT1l, b1, Xn_c, NCTX);
  }

  // edge mean-pool -> Q as bf16 hi/lo
  k_gather<<<dim3(NT, BATCH), 256, 0, stream>>>(Xn_t, Xn_c, knn, XeH, XeL);

  // P dead now -> contrib
  hipMemsetAsync(P, 0, (size_t)BATCH * NCTX * CH * 4, stream);

  // fused edge2node + out_t + scatter atomics
  k_g2f<<<dim3(NT / 32, BATCH), 256, 0, stream>>>(XeH, XeL, WT2h, WT2l, b2, knn, out_t, P);

  k_fin_c<<<dim3(NCTX / 128, CH / 32, BATCH), tb, 0, stream>>>(P, counts, out_c1, out_c2);
}

// Round 16
// 392.102 us; speedup vs baseline: 1.1204x; 1.0006x over previous
//
#include <hip/hip_runtime.h>
#include <math.h>
#include <float.h>

#define BATCH 4
#define CH    256
#define NT    4096
#define NCTX  8192
#define KI    8

// coarse-selection geometry
#define CSEL    10                 // per-split top-C after lane-half merge (>=8+2 slack => safe)
#define DNSPLIT 8                  // ctx splits
#define CTX_PER (NCTX / DNSPLIT)   // 1024
#define NTILE   (CTX_PER / 32)     // 32 tiles of 32 ctx
#define NKEY    (DNSPLIT * CSEL)   // 80 packed keys per target
#define RESC    12                 // keys kept for exact fp64 rescore

typedef __attribute__((ext_vector_type(8)))  __bf16 bf16x8;
typedef __attribute__((ext_vector_type(16))) float  f32x16;

__device__ __forceinline__ unsigned short bf16_rne(float v) {
  unsigned u = __float_as_uint(v);
  return (unsigned short)((u + 0x7fffu + ((u >> 16) & 1u)) >> 16);
}

// ---------------- prep: transpose (128-ch tiles, wide stores) + W transpose, role-fused ----------------
// NOTE: fp32 node-major copies (Q,P) are REQUIRED — the fp64 rescore must consume the exact
// fp32 values the reference uses; bf16 hi/lo reconstruction (R15) flips ~4 rank-8 boundaries.
__global__ __launch_bounds__(256) void k_prep(const float* __restrict__ Xt,
                                              const float* __restrict__ Xc1,
                                              const float* __restrict__ Xc2,
                                              float* __restrict__ Q,
                                              float* __restrict__ P,
                                              unsigned short* __restrict__ XtBh,
                                              unsigned short* __restrict__ XtBl,
                                              unsigned short* __restrict__ XcBh,
                                              unsigned short* __restrict__ XcBl,
                                              float* __restrict__ nrm,
                                              const float* __restrict__ W1,
                                              const float* __restrict__ W2,
                                              unsigned short* __restrict__ WT1h,
                                              unsigned short* __restrict__ WT1l,
                                              unsigned short* __restrict__ WT2h,
                                              unsigned short* __restrict__ WT2l) {
  __shared__ float tile[128][33];   // 16.9 KB
  __shared__ float ps[8][32];
  const int bid = blockIdx.x;
  const int tx = threadIdx.x, ty = threadIdx.y;

  if (bid < 3072) {
    const int x = bid & 127, y = (bid >> 7) & 1, z = bid >> 8;
    const int which = z >> 2, b = z & 3;
    const float* src;
    float* dF; unsigned short *dH, *dL; float* nrmp = nullptr;
    if (which == 0) {
      src = Xt + (long)b * CH * NT;
      dF = Q + (long)b * NT * CH;
      dH = XtBh + (long)b * NT * CH;  dL = XtBl + (long)b * NT * CH;
    } else if (which == 1) {
      src = Xc1 + (long)b * CH * NT;
      dF = P + (long)b * NCTX * CH;
      dH = XcBh + (long)b * NCTX * CH;  dL = XcBl + (long)b * NCTX * CH;
      nrmp = nrm + (long)b * NCTX;
    } else {
      src = Xc2 + (long)b * CH * NT;
      dF = P + ((long)b * NCTX + NT) * CH;
      dH = XcBh + ((long)b * NCTX + NT) * CH;  dL = XcBl + ((long)b * NCTX + NT) * CH;
      nrmp = nrm + (long)b * NCTX + NT;
    }
    const int m0 = x * 32, c0 = y * 128;
    float part = 0.f;
#pragma unroll
    for (int i = ty; i < 128; i += 8) {
      float v = src[(long)(c0 + i) * NT + (m0 + tx)];
      tile[i][tx] = v;
      part = fmaf(v, v, part);
    }
    if (which) ps[ty][tx] = part;
    __syncthreads();
#pragma unroll
    for (int i = ty; i < 32; i += 8) {
      float v0 = tile[4 * tx + 0][i];
      float v1 = tile[4 * tx + 1][i];
      float v2 = tile[4 * tx + 2][i];
      float v3 = tile[4 * tx + 3][i];
      long o = (long)(m0 + i) * CH + (c0 + 4 * tx);
      float4 f4; f4.x = v0; f4.y = v1; f4.z = v2; f4.w = v3;
      *(float4*)&dF[o] = f4;
      unsigned short h0 = bf16_rne(v0), h1 = bf16_rne(v1), h2 = bf16_rne(v2), h3 = bf16_rne(v3);
      ushort4 h4; h4.x = h0; h4.y = h1; h4.z = h2; h4.w = h3;
      *(ushort4*)&dH[o] = h4;
      ushort4 l4;
      l4.x = bf16_rne(v0 - __uint_as_float((unsigned)h0 << 16));
      l4.y = bf16_rne(v1 - __uint_as_float((unsigned)h1 << 16));
      l4.z = bf16_rne(v2 - __uint_as_float((unsigned)h2 << 16));
      l4.w = bf16_rne(v3 - __uint_as_float((unsigned)h3 << 16));
      *(ushort4*)&dL[o] = l4;
    }
    if (which && ty == 0) {
      float s = 0.f;
#pragma unroll
      for (int j = 0; j < 8; ++j) s += ps[j][tx];
      atomicAdd(&nrmp[m0 + tx], -0.5f * s);
    }
  } else {
    const int r = bid - 3072;
    const int n0 = (r & 7) * 32, k0 = ((r >> 3) & 7) * 32;
    const float* W = (r >> 6) ? W2 : W1;
    unsigned short* WTh = (r >> 6) ? WT2h : WT1h;
    unsigned short* WTl = (r >> 6) ? WT2l : WT1l;
#pragma unroll
    for (int i = ty; i < 32; i += 8)
      tile[i][tx] = W[(k0 + i) * CH + (n0 + tx)];
    __syncthreads();
#pragma unroll
    for (int i = ty; i < 32; i += 8) {
      float v = tile[tx][i];
      int o = (n0 + i) * CH + (k0 + tx);
      unsigned short h = bf16_rne(v);
      WTh[o] = h;
      WTl[o] = bf16_rne(v - __uint_as_float((unsigned)h << 16));
    }
  }
}

// ---------------- main: dist (bid<1024, XCD-correct lid=bid) then gemm (bid>=1024, fat only) ----------------
// Sequential role layout (R12/R14-proven): gemm blocks queue behind dist and backfill CUs as
// dist blocks drain. Interleaving regressed (R13): broke XCD locality + displaced dist issue.
__global__ __launch_bounds__(256) void k_main(const __bf16* __restrict__ XcB,
                                              const __bf16* __restrict__ XtB,
                                              const float* __restrict__ nrm,
                                              unsigned* __restrict__ cand,
                                              const unsigned short* __restrict__ XtBh,
                                              const unsigned short* __restrict__ XtBl,
                                              const unsigned short* __restrict__ XcBh,
                                              const unsigned short* __restrict__ XcBl,
                                              const unsigned short* __restrict__ WTh,
                                              const unsigned short* __restrict__ WTl,
                                              const float* __restrict__ bias,
                                              float* __restrict__ outT,
                                              float* __restrict__ outC) {
  __shared__ __bf16 lds[2][32 * CH];   // 32 KB, shared by both roles
  const int bid = blockIdx.x;
  const int t = threadIdx.x, w = t >> 6, lane = t & 63;
  const int l31 = lane & 31, lh = lane >> 5;

  if (bid < 1024) {
    // ---- dist role ----
    const int lid = bid;
    const int xk = lid & 7;
    const int b = xk >> 1, jh = xk & 1;
    const int jw = (lid >> 3) & 15, split = lid >> 7;
    const int tgt0 = (jh * 16 + jw) * 128 + w * 32;
    const int cbase = split * CTX_PER;
    const float* nrmt = nrm + (long)b * NCTX + cbase;

    const __bf16* tp = XtB + ((long)b * NT + tgt0 + l31) * CH + lh * 8;
    bf16x8 bfrag[16];
#pragma unroll
    for (int s = 0; s < 16; ++s) bfrag[s] = *(const bf16x8*)(tp + s * 16);

    unsigned kd[CSEL];
#pragma unroll
    for (int q = 0; q < CSEL; ++q) kd[q] = 0xFFFFFFFFu;

    const __bf16* cp = XcB + ((long)b * NCTX + cbase + l31) * CH;

    auto STAGE = [&](int buf, int jt) {
#pragma unroll
      for (int r = 0; r < 4; ++r) {
        int c = r * 4 + w;
        const __bf16* src = cp + (long)jt * 32 * CH + (c * 2 + lh) * 8;
        __bf16* dst = &lds[buf][c * 512];
        __builtin_amdgcn_global_load_lds((const __attribute__((address_space(1))) void*)src,
                                         (__attribute__((address_space(3))) void*)dst,
                                         16, 0, 0);
      }
    };

    STAGE(0, 0);
    __syncthreads();

    int cur = 0;
    for (int jt = 0; jt < NTILE; ++jt) {
      if (jt + 1 < NTILE) STAGE(cur ^ 1, jt + 1);

      const int ct0 = jt * 32;
      f32x16 acc;
#pragma unroll
      for (int g = 0; g < 4; ++g) {
        float4 nv = *(const float4*)&nrmt[ct0 + 8 * g + 4 * lh];
        acc[4 * g + 0] = nv.x; acc[4 * g + 1] = nv.y;
        acc[4 * g + 2] = nv.z; acc[4 * g + 3] = nv.w;
      }
#pragma unroll
      for (int s = 0; s < 16; ++s) {
        bf16x8 a = *(const bf16x8*)(&lds[cur][s * 512 + lane * 8]);
        acc = __builtin_amdgcn_mfma_f32_32x32x16_bf16(a, bfrag[s], acc, 0, 0, 0);
      }

#pragma unroll
      for (int reg = 0; reg < 16; ++reg) {
        const int row = (reg & 3) + 8 * (reg >> 2) + lh * 4;
        float sc = fmaf(acc[reg], -2.0f, 512.0f);
        unsigned key = (__float_as_uint(sc) & 0xFFFFF800u) | (unsigned)ct0 | (unsigned)row;
#pragma unroll
        for (int q = 0; q < CSEL; ++q) {
          unsigned lo = min(key, kd[q]);
          key = max(key, kd[q]);
          kd[q] = lo;
        }
      }
      __syncthreads();
      cur ^= 1;
    }

    unsigned oth[CSEL];
#pragma unroll
    for (int q = 0; q < CSEL; ++q) oth[q] = (unsigned)__shfl_xor((int)kd[q], 32, 64);
    if (lh == 0) {
      long ob = (((long)b * NT + tgt0 + l31) * DNSPLIT + split) * CSEL;
#pragma unroll
      for (int q = 0; q < CSEL; ++q)
        cand[ob + q] = min(kd[q], oth[CSEL - 1 - q]);
    }
  } else {
    // ---- gemm role (fat mode only) ----
    int g = bid - 1024;
    const unsigned short *Ah, *Al; float* out; int M, m0, b;
    if (g < 512) { Ah = XtBh; Al = XtBl; out = outT; M = NT;   m0 = (g & 127) * 32; b = g >> 7; }
    else { g -= 512; Ah = XcBh; Al = XcBl; out = outC; M = NCTX; m0 = (g & 255) * 32; b = g >> 8; }
    __bf16* ldsH = lds[0];
    __bf16* ldsL = lds[1];
    const long abase = (long)b * M * CH;
    const unsigned short* pH = Ah + abase + (long)(m0 + l31) * CH;
    const unsigned short* pL = Al + abase + (long)(m0 + l31) * CH;
#pragma unroll
    for (int r = 0; r < 4; ++r) {
      int c = r * 4 + w;
      __builtin_amdgcn_global_load_lds(
          (const __attribute__((address_space(1))) void*)(pH + (c * 2 + lh) * 8),
          (__attribute__((address_space(3))) void*)&ldsH[c * 512], 16, 0, 0);
      __builtin_amdgcn_global_load_lds(
          (const __attribute__((address_space(1))) void*)(pL + (c * 2 + lh) * 8),
          (__attribute__((address_space(3))) void*)&ldsL[c * 512], 16, 0, 0);
    }
    __syncthreads();

    const int n0 = w * 64;
    f32x16 acc0, acc1;
#pragma unroll
    for (int i = 0; i < 16; ++i) { acc0[i] = 0.f; acc1[i] = 0.f; }
#pragma unroll
    for (int s = 0; s < 16; ++s) {
      bf16x8 ah = *(const bf16x8*)&ldsH[s * 512 + lane * 8];
      bf16x8 al = *(const bf16x8*)&ldsL[s * 512 + lane * 8];
      const int koff = lh * 8 + s * 16;
      bf16x8 bh0 = *(const bf16x8*)&WTh[(n0 + l31) * CH + koff];
      bf16x8 bl0 = *(const bf16x8*)&WTl[(n0 + l31) * CH + koff];
      bf16x8 bh1 = *(const bf16x8*)&WTh[(n0 + 32 + l31) * CH + koff];
      bf16x8 bl1 = *(const bf16x8*)&WTl[(n0 + 32 + l31) * CH + koff];
      acc0 = __builtin_amdgcn_mfma_f32_32x32x16_bf16(ah, bh0, acc0, 0, 0, 0);
      acc1 = __builtin_amdgcn_mfma_f32_32x32x16_bf16(ah, bh1, acc1, 0, 0, 0);
      acc0 = __builtin_amdgcn_mfma_f32_32x32x16_bf16(ah, bl0, acc0, 0, 0, 0);
      acc1 = __builtin_amdgcn_mfma_f32_32x32x16_bf16(ah, bl1, acc1, 0, 0, 0);
      acc0 = __builtin_amdgcn_mfma_f32_32x32x16_bf16(al, bh0, acc0, 0, 0, 0);
      acc1 = __builtin_amdgcn_mfma_f32_32x32x16_bf16(al, bh1, acc1, 0, 0, 0);
    }
    float* ob = out + abase;
    float bi0 = bias[n0 + l31], bi1 = bias[n0 + 32 + l31];
#pragma unroll
    for (int reg = 0; reg < 16; ++reg) {
      int row = (reg & 3) + 8 * (reg >> 2) + 4 * lh;
      ob[(long)(m0 + row) * CH + n0 + l31]      = acc0[reg] + bi0;
      ob[(long)(m0 + row) * CH + n0 + 32 + l31] = acc1[reg] + bi1;
    }
  }
}

// ---------------- standalone node2edge GEMM (fallback mode) ----------------
__global__ __launch_bounds__(256) void k_gemm_mfma(const unsigned short* __restrict__ Ah,
                                                   const unsigned short* __restrict__ Al,
                                                   const unsigned short* __restrict__ WTh,
                                                   const unsigned short* __restrict__ WTl,
                                                   const float* __restrict__ bias,
                                                   float* __restrict__ out, int M) {
  __shared__ __bf16 ldsH[32 * CH];
  __shared__ __bf16 ldsL[32 * CH];
  const int b = blockIdx.y;
  const int m0 = blockIdx.x * 32;
  const int t = threadIdx.x, w = t >> 6, lane = t & 63;
  const int l31 = lane & 31, lh = lane >> 5;
  const long abase = (long)b * M * CH;
  const unsigned short* pH = Ah + abase + (long)(m0 + l31) * CH;
  const unsigned short* pL = Al + abase + (long)(m0 + l31) * CH;
#pragma unroll
  for (int r = 0; r < 4; ++r) {
    int c = r * 4 + w;
    __builtin_amdgcn_global_load_lds(
        (const __attribute__((address_space(1))) void*)(pH + (c * 2 + lh) * 8),
        (__attribute__((address_space(3))) void*)&ldsH[c * 512], 16, 0, 0);
    __builtin_amdgcn_global_load_lds(
        (const __attribute__((address_space(1))) void*)(pL + (c * 2 + lh) * 8),
        (__attribute__((address_space(3))) void*)&ldsL[c * 512], 16, 0, 0);
  }
  __syncthreads();

  const int n0 = w * 64;
  f32x16 acc0, acc1;
#pragma unroll
  for (int i = 0; i < 16; ++i) { acc0[i] = 0.f; acc1[i] = 0.f; }
#pragma unroll
  for (int s = 0; s < 16; ++s) {
    bf16x8 ah = *(const bf16x8*)&ldsH[s * 512 + lane * 8];
    bf16x8 al = *(const bf16x8*)&ldsL[s * 512 + lane * 8];
    const int koff = lh * 8 + s * 16;
    bf16x8 bh0 = *(const bf16x8*)&WTh[(n0 + l31) * CH + koff];
    bf16x8 bl0 = *(const bf16x8*)&WTl[(n0 + l31) * CH + koff];
    bf16x8 bh1 = *(const bf16x8*)&WTh[(n0 + 32 + l31) * CH + koff];
    bf16x8 bl1 = *(const bf16x8*)&WTl[(n0 + 32 + l31) * CH + koff];
    acc0 = __builtin_amdgcn_mfma_f32_32x32x16_bf16(ah, bh0, acc0, 0, 0, 0);
    acc1 = __builtin_amdgcn_mfma_f32_32x32x16_bf16(ah, bh1, acc1, 0, 0, 0);
    acc0 = __builtin_amdgcn_mfma_f32_32x32x16_bf16(ah, bl0, acc0, 0, 0, 0);
    acc1 = __builtin_amdgcn_mfma_f32_32x32x16_bf16(ah, bl1, acc1, 0, 0, 0);
    acc0 = __builtin_amdgcn_mfma_f32_32x32x16_bf16(al, bh0, acc0, 0, 0, 0);
    acc1 = __builtin_amdgcn_mfma_f32_32x32x16_bf16(al, bh1, acc1, 0, 0, 0);
  }
  float* ob = out + abase;
  float bi0 = bias[n0 + l31], bi1 = bias[n0 + 32 + l31];
#pragma unroll
  for (int reg = 0; reg < 16; ++reg) {
    int row = (reg & 3) + 8 * (reg >> 2) + 4 * lh;
    ob[(long)(m0 + row) * CH + n0 + l31]      = acc0[reg] + bi0;
    ob[(long)(m0 + row) * CH + n0 + 32 + l31] = acc1[reg] + bi1;
  }
}

// ---------------- rescore: 4 targets/block, coarse top-RESC of 80 keys, fp64 exact (fp32 inputs), rank-8 + counts ----------------
__global__ __launch_bounds__(256) void k_rescore(const float* __restrict__ XtT,
                                                 const float* __restrict__ XcT,
                                                 const unsigned* __restrict__ cand,
                                                 int* __restrict__ knn,
                                                 unsigned* __restrict__ counts) {
  const int t = threadIdx.x, sub = t >> 6, lane = t & 63;
  const int n = blockIdx.x * 4 + sub, b = blockIdx.y;
  const int grp = lane >> 4, gl = lane & 15;
  __shared__ unsigned sk[4][NKEY];
  __shared__ int cidx[4][RESC];
  __shared__ double sd[4][RESC];
  __shared__ int sj[4][RESC];
  const unsigned* kp = cand + ((long)b * NT + n) * NKEY;
  unsigned k0 = kp[lane];
  unsigned k1 = (lane < NKEY - 64) ? kp[64 + lane] : 0xFFFFFFFFu;
  sk[sub][lane] = k0;
  if (lane < NKEY - 64) sk[sub][64 + lane] = k1;
  __syncthreads();
  int r0 = 0, r1 = 0;
  for (int i = 0; i < NKEY; ++i) {
    unsigned s = sk[sub][i];
    r0 += (s < k0 || (s == k0 && i < lane)) ? 1 : 0;
    r1 += (s < k1 || (s == k1 && i < 64 + lane)) ? 1 : 0;
  }
  if (r0 < RESC) cidx[sub][r0] = (lane / CSEL) * CTX_PER + (int)(k0 & 0x7FFu);
  if (lane < NKEY - 64 && r1 < RESC)
    cidx[sub][r1] = ((64 + lane) / CSEL) * CTX_PER + (int)(k1 & 0x7FFu);
  __syncthreads();

  const float* xt = XtT + ((long)b * NT + n) * CH + gl * 16;
  double xa[16];
#pragma unroll
  for (int r = 0; r < 4; ++r) {
    float4 v = *(const float4*)(xt + r * 4);
    xa[4 * r + 0] = (double)v.x; xa[4 * r + 1] = (double)v.y;
    xa[4 * r + 2] = (double)v.z; xa[4 * r + 3] = (double)v.w;
  }
#pragma unroll
  for (int q0 = 0; q0 < RESC; q0 += 4) {
    int q = q0 + grp;
    int j = cidx[sub][q];
    const float* xc = XcT + ((long)b * NCTX + j) * CH + gl * 16;
    double acc = 0.0;
#pragma unroll
    for (int r = 0; r < 4; ++r) {
      float4 v = *(const float4*)(xc + r * 4);
      double d0 = xa[4 * r + 0] - (double)v.x; acc = fma(d0, d0, acc);
      double d1 = xa[4 * r + 1] - (double)v.y; acc = fma(d1, d1, acc);
      double d2 = xa[4 * r + 2] - (double)v.z; acc = fma(d2, d2, acc);
      double d3 = xa[4 * r + 3] - (double)v.w; acc = fma(d3, d3, acc);
    }
#pragma unroll
    for (int off = 8; off > 0; off >>= 1) acc += __shfl_xor(acc, off, 64);
    if (gl == 0) { sd[sub][q] = acc; sj[sub][q] = j; }
  }
  __syncthreads();
  double dq = (lane < RESC) ? sd[sub][lane] : DBL_MAX;
  int    jq = (lane < RESC) ? sj[sub][lane] : 0x7fffffff;
  int rank = 0;
#pragma unroll
  for (int i = 0; i < RESC; ++i) {
    double di = sd[sub][i]; int ji = sj[sub][i];
    rank += (di < dq || (di == dq && ji < jq)) ? 1 : 0;
  }
  if (lane < RESC && rank < KI) {
    knn[((long)b * NT + n) * KI + rank] = jq;
    atomicAdd(&counts[(long)b * NCTX + jq], 1u);
  }
}

// ---------------- gather-mean: X_edge = (Xn_t + sum_k Xn_c[knn]) / 9 -> bf16 hi/lo ----------------
__global__ __launch_bounds__(256) void k_gather(const float* __restrict__ Xn_t,
                                                const float* __restrict__ Xn_c,
                                                const int* __restrict__ knn,
                                                unsigned short* __restrict__ XeH,
                                                unsigned short* __restrict__ XeL) {
  const int n = blockIdx.x, b = blockIdx.y, c = threadIdx.x;
  const int* kn = knn + ((long)b * NT + n) * KI;
  int j[KI];
#pragma unroll
  for (int q = 0; q < KI; ++q) j[q] = kn[q];
  float acc = Xn_t[((long)b * NT + n) * CH + c];
#pragma unroll
  for (int q = 0; q < KI; ++q) acc += Xn_c[((long)b * NCTX + j[q]) * CH + c];
  float xe = acc / 9.0f;
  long o = ((long)b * NT + n) * CH + c;
  unsigned short h = bf16_rne(xe);
  XeH[o] = h;
  XeL[o] = bf16_rne(xe - __uint_as_float((unsigned)h << 16));
}

// ---------------- fused edge2node GEMM + out_t + scatter-add (X_et never materialized) ----------------
__global__ __launch_bounds__(256) void k_g2f(const unsigned short* __restrict__ XeH_g,
                                             const unsigned short* __restrict__ XeL_g,
                                             const unsigned short* __restrict__ WTh,
                                             const unsigned short* __restrict__ WTl,
                                             const float* __restrict__ bias,
                                             const int* __restrict__ knn,
                                             float* __restrict__ out_t,
                                             float* __restrict__ contrib) {
  __shared__ char smem[34816];   // phase A/B: 2x16KB Xe staging; phase C: float S[256][33]
  __shared__ int knns[256];      // 32 nodes x 8 neighbors
  __bf16* ldsH = (__bf16*)smem;
  __bf16* ldsL = (__bf16*)(smem + 16384);
  const int b = blockIdx.y;
  const int m0 = blockIdx.x * 32;
  const int t = threadIdx.x, w = t >> 6, lane = t & 63;
  const int l31 = lane & 31, lh = lane >> 5;
  const long abase = (long)b * NT * CH;
  const unsigned short* pH = XeH_g + abase + (long)(m0 + l31) * CH;
  const unsigned short* pL = XeL_g + abase + (long)(m0 + l31) * CH;
#pragma unroll
  for (int r = 0; r < 4; ++r) {
    int c = r * 4 + w;
    __builtin_amdgcn_global_load_lds(
        (const __attribute__((address_space(1))) void*)(pH + (c * 2 + lh) * 8),
        (__attribute__((address_space(3))) void*)&ldsH[c * 512], 16, 0, 0);
    __builtin_amdgcn_global_load_lds(
        (const __attribute__((address_space(1))) void*)(pL + (c * 2 + lh) * 8),
        (__attribute__((address_space(3))) void*)&ldsL[c * 512], 16, 0, 0);
  }
  knns[t] = knn[((long)b * NT + m0 + (t >> 3)) * KI + (t & 7)];
  __syncthreads();

  const unsigned short* wh0 = WTh + (long)(w * 64 + l31) * CH;
  const unsigned short* wl0 = WTl + (long)(w * 64 + l31) * CH;
  f32x16 acc0, acc1;
#pragma unroll
  for (int i = 0; i < 16; ++i) { acc0[i] = 0.f; acc1[i] = 0.f; }
#pragma unroll
  for (int s = 0; s < 16; ++s) {
    const int koff = lh * 8 + s * 16;
    bf16x8 beh = *(const bf16x8*)&ldsH[s * 512 + lane * 8];
    bf16x8 bel = *(const bf16x8*)&ldsL[s * 512 + lane * 8];
    bf16x8 ah0 = *(const bf16x8*)(const __bf16*)(wh0 + koff);
    bf16x8 al0 = *(const bf16x8*)(const __bf16*)(wl0 + koff);
    bf16x8 ah1 = *(const bf16x8*)(const __bf16*)(wh0 + 32 * CH + koff);
    bf16x8 al1 = *(const bf16x8*)(const __bf16*)(wl0 + 32 * CH + koff);
    acc0 = __builtin_amdgcn_mfma_f32_32x32x16_bf16(ah0, beh, acc0, 0, 0, 0);
    acc1 = __builtin_amdgcn_mfma_f32_32x32x16_bf16(ah1, beh, acc1, 0, 0, 0);
    acc0 = __builtin_amdgcn_mfma_f32_32x32x16_bf16(al0, beh, acc0, 0, 0, 0);
    acc1 = __builtin_amdgcn_mfma_f32_32x32x16_bf16(al1, beh, acc1, 0, 0, 0);
    acc0 = __builtin_amdgcn_mfma_f32_32x32x16_bf16(ah0, bel, acc0, 0, 0, 0);
    acc1 = __builtin_amdgcn_mfma_f32_32x32x16_bf16(ah1, bel, acc1, 0, 0, 0);
  }
  __syncthreads();   // staging reads done; smem reusable as S

  float* S = (float*)smem;               // [256][33]
  float* ot = out_t + (long)b * CH * NT + m0;
#pragma unroll
  for (int reg = 0; reg < 16; ++reg) {
    const int row = (reg & 3) + 8 * (reg >> 2) + 4 * lh;
    const int ch0 = w * 64 + row, ch1 = ch0 + 32;
    float v0 = acc0[reg] + bias[ch0];
    float v1 = acc1[reg] + bias[ch1];
    S[ch0 * 33 + l31] = v0;
    S[ch1 * 33 + l31] = v1;
    ot[(long)ch0 * NT + l31] = v0;
    ot[(long)ch1 * NT + l31] = v1;
  }
  __syncthreads();

  // scatter: per node nn, all 256 threads = 256 channels, coalesced atomics
  float* cb = contrib + (long)b * NCTX * CH;
#pragma unroll 4
  for (int nn = 0; nn < 32; ++nn) {
    float v = S[t * 33 + nn];
    const int* kn = &knns[nn * 8];
#pragma unroll
    for (int q = 0; q < KI; ++q)
      atomicAdd(&cb[(long)kn[q] * CH + t], v);
  }
}

// ---------------- finalize context outputs: /counts, transpose (128-j tiles, float4 stores) ----------------
__global__ __launch_bounds__(256) void k_fin_c(const float* __restrict__ contrib,
                                               const unsigned* __restrict__ counts,
                                               float* __restrict__ out1,
                                               float* __restrict__ out2) {
  __shared__ float tile[128][33];
  const int b = blockIdx.z;
  const int j0 = blockIdx.x * 128, c0 = blockIdx.y * 32;
  const int tx = threadIdx.x, ty = threadIdx.y;
#pragma unroll
  for (int i = ty; i < 128; i += 8) {
    float cnt = fmaxf((float)counts[(long)b * NCTX + j0 + i], 1.0f);
    tile[i][tx] = contrib[((long)b * NCTX + j0 + i) * CH + c0 + tx] * (1.0f / cnt);
  }
  __syncthreads();
  float* outp = (j0 < NT) ? (out1 + (long)b * CH * NT + j0)
                          : (out2 + (long)b * CH * NT + (j0 - NT));
#pragma unroll
  for (int i = ty; i < 32; i += 8) {
    float4 v;
    v.x = tile[4 * tx + 0][i];
    v.y = tile[4 * tx + 1][i];
    v.z = tile[4 * tx + 2][i];
    v.w = tile[4 * tx + 3][i];
    *(float4*)&outp[(long)(c0 + i) * NT + 4 * tx] = v;
  }
}

extern "C" void kernel_launch(void* const* d_in, const int* in_sizes, int n_in,
                              void* d_out, int out_size, void* d_ws, size_t ws_size,
                              hipStream_t stream) {
  const float* Xt  = (const float*)d_in[0];
  const float* Xc1 = (const float*)d_in[1];
  const float* Xc2 = (const float*)d_in[2];
  const float* W1  = (const float*)d_in[3];
  const float* b1  = (const float*)d_in[4];
  const float* W2  = (const float*)d_in[5];
  const float* b2  = (const float*)d_in[6];
  float* out = (float*)d_out;

  // common ws layout (68.42 MB)
  float* P = (float*)d_ws;                               // XcT -> (fallback Xn_c) -> contrib
  float* Q = P + (long)BATCH * NCTX * CH;                // XtT -> XeH/XeL
  float* R = Q + (long)BATCH * NT * CH;                  // (fallback cand) -> Xn_t
  float* nrm = R + (long)BATCH * NT * CH;
  unsigned* counts = (unsigned*)(nrm + (long)BATCH * NCTX);
  int* knn = (int*)(counts + (long)BATCH * NCTX);
  unsigned short* WT1h = (unsigned short*)(knn + (long)BATCH * NT * KI);
  unsigned short* WT1l = WT1h + CH * CH;
  unsigned short* WT2h = WT1l + CH * CH;
  unsigned short* WT2l = WT2h + CH * CH;
  // fat-mode extras: separate Xn_c (33.55 MB) + cand (5.24 MB)
  float* Xn_c_fat = (float*)(WT2l + CH * CH);
  unsigned* cand_fat = (unsigned*)(Xn_c_fat + (long)BATCH * NCTX * CH);
  const size_t need_fat = (size_t)((char*)(cand_fat + (long)BATCH * NT * NKEY) - (char*)d_ws);
  const bool fat = ws_size >= need_fat;

  unsigned* cand = fat ? cand_fat : (unsigned*)R;
  float* Xn_c = fat ? Xn_c_fat : P;
  float* Xn_t = R;

  unsigned short* XcBh = (unsigned short*)d_out;
  unsigned short* XtBh = XcBh + (long)BATCH * NCTX * CH;
  unsigned short* XcBl = XtBh + (long)BATCH * NT * CH;
  unsigned short* XtBl = XcBl + (long)BATCH * NCTX * CH;

  unsigned short* XeH = (unsigned short*)Q;   // after rescore, Q (XtT) is dead
  unsigned short* XeL = XeH + (long)BATCH * NT * CH;

  float* out_t  = out;             // overwrites dead XcBh region
  float* out_c1 = out + (long)BATCH * CH * NT;
  float* out_c2 = out + 2L * BATCH * CH * NT;

  dim3 tb(32, 8);

  hipMemsetAsync(nrm, 0, (size_t)BATCH * NCTX * 8, stream);   // nrm + counts

  k_prep<<<dim3(3072 + 128), tb, 0, stream>>>(Xt, Xc1, Xc2, Q, P, XtBh, XtBl, XcBh, XcBl, nrm,
                                              W1, W2, WT1h, WT1l, WT2h, WT2l);

  if (fat) {
    // dist (XCD-correct bids 0..1023) + both node2edge GEMMs queued behind (R12-proven layout)
    k_main<<<dim3(1024 + 512 + 1024), 256, 0, stream>>>(
        (const __bf16*)XcBh, (const __bf16*)XtBh, nrm, cand,
        XtBh, XtBl, XcBh, XcBl, WT1h, WT1l, b1, Xn_t, Xn_c);
    k_rescore<<<dim3(NT / 4, BATCH), 256, 0, stream>>>(Q, P, cand, knn, counts);
  } else {
    k_main<<<dim3(1024), 256, 0, stream>>>(
        (const __bf16*)XcBh, (const __bf16*)XtBh, nrm, cand,
        XtBh, XtBl, XcBh, XcBl, WT1h, WT1l, b1, Xn_t, Xn_c);
    k_rescore<<<dim3(NT / 4, BATCH), 256, 0, stream>>>(Q, P, cand, knn, counts);
    k_gemm_mfma<<<dim3(NT / 32, BATCH), 256, 0, stream>>>(XtBh, XtBl, WT1h, WT1l, b1, Xn_t, NT);
    k_gemm_mfma<<<dim3(NCTX / 32, BATCH), 256, 0, stream>>>(XcBh, XcBl, WT1h, WT1l, b1, Xn_c, NCTX);
  }

  // edge mean-pool -> Q as bf16 hi/lo
  k_gather<<<dim3(NT, BATCH), 256, 0, stream>>>(Xn_t, Xn_c, knn, XeH, XeL);

  // P dead now -> contrib
  hipMemsetAsync(P, 0, (size_t)BATCH * NCTX * CH * 4, stream);

  // fused edge2node + out_t + scatter atomics
  k_g2f<<<dim3(NT / 32, BATCH), 256, 0, stream>>>(XeH, XeL, WT2h, WT2l, b2, knn, out_t, P);

  k_fin_c<<<dim3(NCTX / 128, CH / 32, BATCH), tb, 0, stream>>>(P, counts, out_c1, out_c2);
}

// Round 18
// 387.831 us; speedup vs baseline: 1.1327x; 1.0110x over previous
//
#include <hip/hip_runtime.h>
#include <math.h>
#include <float.h>

#define BATCH 4
#define CH    256
#define NT    4096
#define NCTX  8192
#define KI    8

// coarse-selection geometry
#define CSEL    10                 // per-split top-C after lane-half merge (>=8+2 slack => safe)
#define DNSPLIT 8                  // ctx splits
#define CTX_PER (NCTX / DNSPLIT)   // 1024
#define NTILE   (CTX_PER / 32)     // 32 tiles of 32 ctx
#define NKEY    (DNSPLIT * CSEL)   // 80 packed keys per target
#define RESC    12                 // keys kept for exact fp64 rescore

typedef __attribute__((ext_vector_type(8)))  __bf16 bf16x8;
typedef __attribute__((ext_vector_type(16))) float  f32x16;

__device__ __forceinline__ unsigned short bf16_rne(float v) {
  unsigned u = __float_as_uint(v);
  return (unsigned short)((u + 0x7fffu + ((u >> 16) & 1u)) >> 16);
}

// ---------------- prep: transpose (128-ch tiles, wide stores) + W transpose, role-fused ----------------
// NOTE: fp32 node-major copies (Q,P) are REQUIRED — the fp64 rescore must consume the exact
// fp32 values the reference uses; bf16 hi/lo reconstruction (R15) flips ~4 rank-8 boundaries.
__global__ __launch_bounds__(256) void k_prep(const float* __restrict__ Xt,
                                              const float* __restrict__ Xc1,
                                              const float* __restrict__ Xc2,
                                              float* __restrict__ Q,
                                              float* __restrict__ P,
                                              unsigned short* __restrict__ XtBh,
                                              unsigned short* __restrict__ XtBl,
                                              unsigned short* __restrict__ XcBh,
                                              unsigned short* __restrict__ XcBl,
                                              float* __restrict__ nrm,
                                              const float* __restrict__ W1,
                                              const float* __restrict__ W2,
                                              unsigned short* __restrict__ WT1h,
                                              unsigned short* __restrict__ WT1l,
                                              unsigned short* __restrict__ WT2h,
                                              unsigned short* __restrict__ WT2l) {
  __shared__ float tile[128][33];   // 16.9 KB
  __shared__ float ps[8][32];
  const int bid = blockIdx.x;
  const int tx = threadIdx.x, ty = threadIdx.y;

  if (bid < 3072) {
    const int x = bid & 127, y = (bid >> 7) & 1, z = bid >> 8;
    const int which = z >> 2, b = z & 3;
    const float* src;
    float* dF; unsigned short *dH, *dL; float* nrmp = nullptr;
    if (which == 0) {
      src = Xt + (long)b * CH * NT;
      dF = Q + (long)b * NT * CH;
      dH = XtBh + (long)b * NT * CH;  dL = XtBl + (long)b * NT * CH;
    } else if (which == 1) {
      src = Xc1 + (long)b * CH * NT;
      dF = P + (long)b * NCTX * CH;
      dH = XcBh + (long)b * NCTX * CH;  dL = XcBl + (long)b * NCTX * CH;
      nrmp = nrm + (long)b * NCTX;
    } else {
      src = Xc2 + (long)b * CH * NT;
      dF = P + ((long)b * NCTX + NT) * CH;
      dH = XcBh + ((long)b * NCTX + NT) * CH;  dL = XcBl + ((long)b * NCTX + NT) * CH;
      nrmp = nrm + (long)b * NCTX + NT;
    }
    const int m0 = x * 32, c0 = y * 128;
    float part = 0.f;
#pragma unroll
    for (int i = ty; i < 128; i += 8) {
      float v = src[(long)(c0 + i) * NT + (m0 + tx)];
      tile[i][tx] = v;
      part = fmaf(v, v, part);
    }
    if (which) ps[ty][tx] = part;
    __syncthreads();
#pragma unroll
    for (int i = ty; i < 32; i += 8) {
      float v0 = tile[4 * tx + 0][i];
      float v1 = tile[4 * tx + 1][i];
      float v2 = tile[4 * tx + 2][i];
      float v3 = tile[4 * tx + 3][i];
      long o = (long)(m0 + i) * CH + (c0 + 4 * tx);
      float4 f4; f4.x = v0; f4.y = v1; f4.z = v2; f4.w = v3;
      *(float4*)&dF[o] = f4;
      unsigned short h0 = bf16_rne(v0), h1 = bf16_rne(v1), h2 = bf16_rne(v2), h3 = bf16_rne(v3);
      ushort4 h4; h4.x = h0; h4.y = h1; h4.z = h2; h4.w = h3;
      *(ushort4*)&dH[o] = h4;
      ushort4 l4;
      l4.x = bf16_rne(v0 - __uint_as_float((unsigned)h0 << 16));
      l4.y = bf16_rne(v1 - __uint_as_float((unsigned)h1 << 16));
      l4.z = bf16_rne(v2 - __uint_as_float((unsigned)h2 << 16));
      l4.w = bf16_rne(v3 - __uint_as_float((unsigned)h3 << 16));
      *(ushort4*)&dL[o] = l4;
    }
    if (which && ty == 0) {
      float s = 0.f;
#pragma unroll
      for (int j = 0; j < 8; ++j) s += ps[j][tx];
      atomicAdd(&nrmp[m0 + tx], -0.5f * s);
    }
  } else {
    const int r = bid - 3072;
    const int n0 = (r & 7) * 32, k0 = ((r >> 3) & 7) * 32;
    const float* W = (r >> 6) ? W2 : W1;
    unsigned short* WTh = (r >> 6) ? WT2h : WT1h;
    unsigned short* WTl = (r >> 6) ? WT2l : WT1l;
#pragma unroll
    for (int i = ty; i < 32; i += 8)
      tile[i][tx] = W[(k0 + i) * CH + (n0 + tx)];
    __syncthreads();
#pragma unroll
    for (int i = ty; i < 32; i += 8) {
      float v = tile[tx][i];
      int o = (n0 + i) * CH + (k0 + tx);
      unsigned short h = bf16_rne(v);
      WTh[o] = h;
      WTl[o] = bf16_rne(v - __uint_as_float((unsigned)h << 16));
    }
  }
}

// ---------------- main: dist (bid<1024, XCD-correct lid=bid) then gemm (bid>=1024, fat only) ----------------
__global__ __launch_bounds__(256) void k_main(const __bf16* __restrict__ XcB,
                                              const __bf16* __restrict__ XtB,
                                              const float* __restrict__ nrm,
                                              unsigned* __restrict__ cand,
                                              const unsigned short* __restrict__ XtBh,
                                              const unsigned short* __restrict__ XtBl,
                                              const unsigned short* __restrict__ XcBh,
                                              const unsigned short* __restrict__ XcBl,
                                              const unsigned short* __restrict__ WTh,
                                              const unsigned short* __restrict__ WTl,
                                              const float* __restrict__ bias,
                                              float* __restrict__ outT,
                                              float* __restrict__ outC) {
  __shared__ __bf16 lds[2][32 * CH];   // 32 KB, shared by both roles
  const int bid = blockIdx.x;
  const int t = threadIdx.x, w = t >> 6, lane = t & 63;
  const int l31 = lane & 31, lh = lane >> 5;

  if (bid < 1024) {
    // ---- dist role ----
    const int lid = bid;
    const int xk = lid & 7;
    const int b = xk >> 1, jh = xk & 1;
    const int jw = (lid >> 3) & 15, split = lid >> 7;
    const int tgt0 = (jh * 16 + jw) * 128 + w * 32;
    const int cbase = split * CTX_PER;
    const float* nrmt = nrm + (long)b * NCTX + cbase;

    const __bf16* tp = XtB + ((long)b * NT + tgt0 + l31) * CH + lh * 8;
    bf16x8 bfrag[16];
#pragma unroll
    for (int s = 0; s < 16; ++s) bfrag[s] = *(const bf16x8*)(tp + s * 16);

    unsigned kd[CSEL];
#pragma unroll
    for (int q = 0; q < CSEL; ++q) kd[q] = 0xFFFFFFFFu;

    const __bf16* cp = XcB + ((long)b * NCTX + cbase + l31) * CH;

    auto STAGE = [&](int buf, int jt) {
#pragma unroll
      for (int r = 0; r < 4; ++r) {
        int c = r * 4 + w;
        const __bf16* src = cp + (long)jt * 32 * CH + (c * 2 + lh) * 8;
        __bf16* dst = &lds[buf][c * 512];
        __builtin_amdgcn_global_load_lds((const __attribute__((address_space(1))) void*)src,
                                         (__attribute__((address_space(3))) void*)dst,
                                         16, 0, 0);
      }
    };

    STAGE(0, 0);
    __syncthreads();

    int cur = 0;
    for (int jt = 0; jt < NTILE; ++jt) {
      if (jt + 1 < NTILE) STAGE(cur ^ 1, jt + 1);

      const int ct0 = jt * 32;
      f32x16 acc;
#pragma unroll
      for (int g = 0; g < 4; ++g) {
        float4 nv = *(const float4*)&nrmt[ct0 + 8 * g + 4 * lh];
        acc[4 * g + 0] = nv.x; acc[4 * g + 1] = nv.y;
        acc[4 * g + 2] = nv.z; acc[4 * g + 3] = nv.w;
      }
#pragma unroll
      for (int s = 0; s < 16; ++s) {
        bf16x8 a = *(const bf16x8*)(&lds[cur][s * 512 + lane * 8]);
        acc = __builtin_amdgcn_mfma_f32_32x32x16_bf16(a, bfrag[s], acc, 0, 0, 0);
      }

#pragma unroll
      for (int reg = 0; reg < 16; ++reg) {
        const int row = (reg & 3) + 8 * (reg >> 2) + lh * 4;
        float sc = fmaf(acc[reg], -2.0f, 512.0f);
        unsigned key = (__float_as_uint(sc) & 0xFFFFF800u) | (unsigned)ct0 | (unsigned)row;
#pragma unroll
        for (int q = 0; q < CSEL; ++q) {
          unsigned lo = min(key, kd[q]);
          key = max(key, kd[q]);
          kd[q] = lo;
        }
      }
      __syncthreads();
      cur ^= 1;
    }

    unsigned oth[CSEL];
#pragma unroll
    for (int q = 0; q < CSEL; ++q) oth[q] = (unsigned)__shfl_xor((int)kd[q], 32, 64);
    if (lh == 0) {
      long ob = (((long)b * NT + tgt0 + l31) * DNSPLIT + split) * CSEL;
#pragma unroll
      for (int q = 0; q < CSEL; ++q)
        cand[ob + q] = min(kd[q], oth[CSEL - 1 - q]);
    }
  } else {
    // ---- gemm role (fat mode only) ----
    int g = bid - 1024;
    const unsigned short *Ah, *Al; float* out; int M, m0, b;
    if (g < 512) { Ah = XtBh; Al = XtBl; out = outT; M = NT;   m0 = (g & 127) * 32; b = g >> 7; }
    else { g -= 512; Ah = XcBh; Al = XcBl; out = outC; M = NCTX; m0 = (g & 255) * 32; b = g >> 8; }
    __bf16* ldsH = lds[0];
    __bf16* ldsL = lds[1];
    const long abase = (long)b * M * CH;
    const unsigned short* pH = Ah + abase + (long)(m0 + l31) * CH;
    const unsigned short* pL = Al + abase + (long)(m0 + l31) * CH;
#pragma unroll
    for (int r = 0; r < 4; ++r) {
      int c = r * 4 + w;
      __builtin_amdgcn_global_load_lds(
          (const __attribute__((address_space(1))) void*)(pH + (c * 2 + lh) * 8),
          (__attribute__((address_space(3))) void*)&ldsH[c * 512], 16, 0, 0);
      __builtin_amdgcn_global_load_lds(
          (const __attribute__((address_space(1))) void*)(pL + (c * 2 + lh) * 8),
          (__attribute__((address_space(3))) void*)&ldsL[c * 512], 16, 0, 0);
    }
    __syncthreads();

    const int n0 = w * 64;
    f32x16 acc0, acc1;
#pragma unroll
    for (int i = 0; i < 16; ++i) { acc0[i] = 0.f; acc1[i] = 0.f; }
#pragma unroll
    for (int s = 0; s < 16; ++s) {
      bf16x8 ah = *(const bf16x8*)&ldsH[s * 512 + lane * 8];
      bf16x8 al = *(const bf16x8*)&ldsL[s * 512 + lane * 8];
      const int koff = lh * 8 + s * 16;
      bf16x8 bh0 = *(const bf16x8*)&WTh[(n0 + l31) * CH + koff];
      bf16x8 bl0 = *(const bf16x8*)&WTl[(n0 + l31) * CH + koff];
      bf16x8 bh1 = *(const bf16x8*)&WTh[(n0 + 32 + l31) * CH + koff];
      bf16x8 bl1 = *(const bf16x8*)&WTl[(n0 + 32 + l31) * CH + koff];
      acc0 = __builtin_amdgcn_mfma_f32_32x32x16_bf16(ah, bh0, acc0, 0, 0, 0);
      acc1 = __builtin_amdgcn_mfma_f32_32x32x16_bf16(ah, bh1, acc1, 0, 0, 0);
      acc0 = __builtin_amdgcn_mfma_f32_32x32x16_bf16(ah, bl0, acc0, 0, 0, 0);
      acc1 = __builtin_amdgcn_mfma_f32_32x32x16_bf16(ah, bl1, acc1, 0, 0, 0);
      acc0 = __builtin_amdgcn_mfma_f32_32x32x16_bf16(al, bh0, acc0, 0, 0, 0);
      acc1 = __builtin_amdgcn_mfma_f32_32x32x16_bf16(al, bh1, acc1, 0, 0, 0);
    }
    float* ob = out + abase;
    float bi0 = bias[n0 + l31], bi1 = bias[n0 + 32 + l31];
#pragma unroll
    for (int reg = 0; reg < 16; ++reg) {
      int row = (reg & 3) + 8 * (reg >> 2) + 4 * lh;
      ob[(long)(m0 + row) * CH + n0 + l31]      = acc0[reg] + bi0;
      ob[(long)(m0 + row) * CH + n0 + 32 + l31] = acc1[reg] + bi1;
    }
  }
}

// ---------------- standalone node2edge GEMM (fallback mode) ----------------
__global__ __launch_bounds__(256) void k_gemm_mfma(const unsigned short* __restrict__ Ah,
                                                   const unsigned short* __restrict__ Al,
                                                   const unsigned short* __restrict__ WTh,
                                                   const unsigned short* __restrict__ WTl,
                                                   const float* __restrict__ bias,
                                                   float* __restrict__ out, int M) {
  __shared__ __bf16 ldsH[32 * CH];
  __shared__ __bf16 ldsL[32 * CH];
  const int b = blockIdx.y;
  const int m0 = blockIdx.x * 32;
  const int t = threadIdx.x, w = t >> 6, lane = t & 63;
  const int l31 = lane & 31, lh = lane >> 5;
  const long abase = (long)b * M * CH;
  const unsigned short* pH = Ah + abase + (long)(m0 + l31) * CH;
  const unsigned short* pL = Al + abase + (long)(m0 + l31) * CH;
#pragma unroll
  for (int r = 0; r < 4; ++r) {
    int c = r * 4 + w;
    __builtin_amdgcn_global_load_lds(
        (const __attribute__((address_space(1))) void*)(pH + (c * 2 + lh) * 8),
        (__attribute__((address_space(3))) void*)&ldsH[c * 512], 16, 0, 0);
    __builtin_amdgcn_global_load_lds(
        (const __attribute__((address_space(1))) void*)(pL + (c * 2 + lh) * 8),
        (__attribute__((address_space(3))) void*)&ldsL[c * 512], 16, 0, 0);
  }
  __syncthreads();

  const int n0 = w * 64;
  f32x16 acc0, acc1;
#pragma unroll
  for (int i = 0; i < 16; ++i) { acc0[i] = 0.f; acc1[i] = 0.f; }
#pragma unroll
  for (int s = 0; s < 16; ++s) {
    bf16x8 ah = *(const bf16x8*)&ldsH[s * 512 + lane * 8];
    bf16x8 al = *(const bf16x8*)&ldsL[s * 512 + lane * 8];
    const int koff = lh * 8 + s * 16;
    bf16x8 bh0 = *(const bf16x8*)&WTh[(n0 + l31) * CH + koff];
    bf16x8 bl0 = *(const bf16x8*)&WTl[(n0 + l31) * CH + koff];
    bf16x8 bh1 = *(const bf16x8*)&WTh[(n0 + 32 + l31) * CH + koff];
    bf16x8 bl1 = *(const bf16x8*)&WTl[(n0 + 32 + l31) * CH + koff];
    acc0 = __builtin_amdgcn_mfma_f32_32x32x16_bf16(ah, bh0, acc0, 0, 0, 0);
    acc1 = __builtin_amdgcn_mfma_f32_32x32x16_bf16(ah, bh1, acc1, 0, 0, 0);
    acc0 = __builtin_amdgcn_mfma_f32_32x32x16_bf16(ah, bl0, acc0, 0, 0, 0);
    acc1 = __builtin_amdgcn_mfma_f32_32x32x16_bf16(ah, bl1, acc1, 0, 0, 0);
    acc0 = __builtin_amdgcn_mfma_f32_32x32x16_bf16(al, bh0, acc0, 0, 0, 0);
    acc1 = __builtin_amdgcn_mfma_f32_32x32x16_bf16(al, bh1, acc1, 0, 0, 0);
  }
  float* ob = out + abase;
  float bi0 = bias[n0 + l31], bi1 = bias[n0 + 32 + l31];
#pragma unroll
  for (int reg = 0; reg < 16; ++reg) {
    int row = (reg & 3) + 8 * (reg >> 2) + 4 * lh;
    ob[(long)(m0 + row) * CH + n0 + l31]      = acc0[reg] + bi0;
    ob[(long)(m0 + row) * CH + n0 + 32 + l31] = acc1[reg] + bi1;
  }
}

// ---------------- rescore: 4 targets/block, coarse top-RESC, fp64 exact (fp32 inputs), rank-8 + counts,
// then (fat) fused gather-mean -> Xe ROW-INTERLEAVED [256 hi | 256 lo] ushorts = 1KB = one fp32 Q row.
// Each block overwrites ONLY its own 4 targets' Q rows, strictly after its last read of them;
// no other block reads those rows (candidates come from P) -> no cross-block hazard (R17 bug fixed).
__global__ __launch_bounds__(256) void k_rescore(const float* __restrict__ XtT,
                                                 const float* __restrict__ XcT,
                                                 const unsigned* __restrict__ cand,
                                                 int* __restrict__ knn,
                                                 unsigned* __restrict__ counts,
                                                 const float* __restrict__ XnT,
                                                 const float* __restrict__ XnC,
                                                 unsigned short* __restrict__ XeHL,
                                                 int do_gather) {
  const int t = threadIdx.x, sub = t >> 6, lane = t & 63;
  const int n = blockIdx.x * 4 + sub, b = blockIdx.y;
  const int grp = lane >> 4, gl = lane & 15;
  __shared__ unsigned sk[4][NKEY];
  __shared__ int cidx[4][RESC];
  __shared__ double sd[4][RESC];
  __shared__ int sj[4][RESC];
  __shared__ int knn_s[4][KI];
  const unsigned* kp = cand + ((long)b * NT + n) * NKEY;
  unsigned k0 = kp[lane];
  unsigned k1 = (lane < NKEY - 64) ? kp[64 + lane] : 0xFFFFFFFFu;
  sk[sub][lane] = k0;
  if (lane < NKEY - 64) sk[sub][64 + lane] = k1;
  __syncthreads();
  int r0 = 0, r1 = 0;
  for (int i = 0; i < NKEY; ++i) {
    unsigned s = sk[sub][i];
    r0 += (s < k0 || (s == k0 && i < lane)) ? 1 : 0;
    r1 += (s < k1 || (s == k1 && i < 64 + lane)) ? 1 : 0;
  }
  if (r0 < RESC) cidx[sub][r0] = (lane / CSEL) * CTX_PER + (int)(k0 & 0x7FFu);
  if (lane < NKEY - 64 && r1 < RESC)
    cidx[sub][r1] = ((64 + lane) / CSEL) * CTX_PER + (int)(k1 & 0x7FFu);
  __syncthreads();

  const float* xt = XtT + ((long)b * NT + n) * CH + gl * 16;
  double xa[16];
#pragma unroll
  for (int r = 0; r < 4; ++r) {
    float4 v = *(const float4*)(xt + r * 4);
    xa[4 * r + 0] = (double)v.x; xa[4 * r + 1] = (double)v.y;
    xa[4 * r + 2] = (double)v.z; xa[4 * r + 3] = (double)v.w;
  }
#pragma unroll
  for (int q0 = 0; q0 < RESC; q0 += 4) {
    int q = q0 + grp;
    int j = cidx[sub][q];
    const float* xc = XcT + ((long)b * NCTX + j) * CH + gl * 16;
    double acc = 0.0;
#pragma unroll
    for (int r = 0; r < 4; ++r) {
      float4 v = *(const float4*)(xc + r * 4);
      double d0 = xa[4 * r + 0] - (double)v.x; acc = fma(d0, d0, acc);
      double d1 = xa[4 * r + 1] - (double)v.y; acc = fma(d1, d1, acc);
      double d2 = xa[4 * r + 2] - (double)v.z; acc = fma(d2, d2, acc);
      double d3 = xa[4 * r + 3] - (double)v.w; acc = fma(d3, d3, acc);
    }
#pragma unroll
    for (int off = 8; off > 0; off >>= 1) acc += __shfl_xor(acc, off, 64);
    if (gl == 0) { sd[sub][q] = acc; sj[sub][q] = j; }
  }
  __syncthreads();
  double dq = (lane < RESC) ? sd[sub][lane] : DBL_MAX;
  int    jq = (lane < RESC) ? sj[sub][lane] : 0x7fffffff;
  int rank = 0;
#pragma unroll
  for (int i = 0; i < RESC; ++i) {
    double di = sd[sub][i]; int ji = sj[sub][i];
    rank += (di < dq || (di == dq && ji < jq)) ? 1 : 0;
  }
  if (lane < RESC && rank < KI) {
    knn[((long)b * NT + n) * KI + rank] = jq;
    knn_s[sub][rank] = jq;
    atomicAdd(&counts[(long)b * NCTX + jq], 1u);
  }

  if (do_gather) {
    __syncthreads();   // all Q-row reads done; knn_s[sub][0..7] fully written
    const int c = lane * 4;
    float4 a = *(const float4*)(XnT + ((long)b * NT + n) * CH + c);
    float a0 = a.x, a1 = a.y, a2 = a.z, a3 = a.w;
    const float* cb = XnC + (long)b * NCTX * CH;
#pragma unroll
    for (int q = 0; q < KI; ++q) {
      float4 v = *(const float4*)(cb + (long)knn_s[sub][q] * CH + c);
      a0 += v.x; a1 += v.y; a2 += v.z; a3 += v.w;
    }
    a0 /= 9.0f; a1 /= 9.0f; a2 /= 9.0f; a3 /= 9.0f;
    unsigned short h0 = bf16_rne(a0), h1 = bf16_rne(a1), h2 = bf16_rne(a2), h3 = bf16_rne(a3);
    ushort4 h4; h4.x = h0; h4.y = h1; h4.z = h2; h4.w = h3;
    ushort4 l4;
    l4.x = bf16_rne(a0 - __uint_as_float((unsigned)h0 << 16));
    l4.y = bf16_rne(a1 - __uint_as_float((unsigned)h1 << 16));
    l4.z = bf16_rne(a2 - __uint_as_float((unsigned)h2 << 16));
    l4.w = bf16_rne(a3 - __uint_as_float((unsigned)h3 << 16));
    unsigned short* xe_row = XeHL + ((long)b * NT + n) * 512;   // 1 KB row = fp32 row n of Q
    *(ushort4*)&xe_row[c] = h4;
    *(ushort4*)&xe_row[256 + c] = l4;
  }
}

// ---------------- standalone gather (fallback mode), row-interleaved Xe layout ----------------
__global__ __launch_bounds__(256) void k_gather(const float* __restrict__ Xn_t,
                                                const float* __restrict__ Xn_c,
                                                const int* __restrict__ knn,
                                                unsigned short* __restrict__ XeHL) {
  const int n = blockIdx.x, b = blockIdx.y, c = threadIdx.x;
  const int* kn = knn + ((long)b * NT + n) * KI;
  int j[KI];
#pragma unroll
  for (int q = 0; q < KI; ++q) j[q] = kn[q];
  float acc = Xn_t[((long)b * NT + n) * CH + c];
#pragma unroll
  for (int q = 0; q < KI; ++q) acc += Xn_c[((long)b * NCTX + j[q]) * CH + c];
  float xe = acc / 9.0f;
  unsigned short h = bf16_rne(xe);
  unsigned short* xe_row = XeHL + ((long)b * NT + n) * 512;
  xe_row[c] = h;
  xe_row[256 + c] = bf16_rne(xe - __uint_as_float((unsigned)h << 16));
}

// ---------------- fused edge2node GEMM + out_t + scatter-add (X_et never materialized) ----------------
// Xe layout: row-interleaved [256 hi | 256 lo] ushorts, row pitch 512.
__global__ __launch_bounds__(256) void k_g2f(const unsigned short* __restrict__ XeHL,
                                             const unsigned short* __restrict__ WTh,
                                             const unsigned short* __restrict__ WTl,
                                             const float* __restrict__ bias,
                                             const int* __restrict__ knn,
                                             float* __restrict__ out_t,
                                             float* __restrict__ contrib) {
  __shared__ char smem[34816];   // phase A/B: 2x16KB Xe staging; phase C: float S[256][33]
  __shared__ int knns[256];      // 32 nodes x 8 neighbors
  __bf16* ldsH = (__bf16*)smem;
  __bf16* ldsL = (__bf16*)(smem + 16384);
  const int b = blockIdx.y;
  const int m0 = blockIdx.x * 32;
  const int t = threadIdx.x, w = t >> 6, lane = t & 63;
  const int l31 = lane & 31, lh = lane >> 5;
  const unsigned short* prow = XeHL + ((long)b * NT + m0 + l31) * 512;
#pragma unroll
  for (int r = 0; r < 4; ++r) {
    int c = r * 4 + w;
    __builtin_amdgcn_global_load_lds(
        (const __attribute__((address_space(1))) void*)(prow + (c * 2 + lh) * 8),
        (__attribute__((address_space(3))) void*)&ldsH[c * 512], 16, 0, 0);
    __builtin_amdgcn_global_load_lds(
        (const __attribute__((address_space(1))) void*)(prow + 256 + (c * 2 + lh) * 8),
        (__attribute__((address_space(3))) void*)&ldsL[c * 512], 16, 0, 0);
  }
  knns[t] = knn[((long)b * NT + m0 + (t >> 3)) * KI + (t & 7)];
  __syncthreads();

  const unsigned short* wh0 = WTh + (long)(w * 64 + l31) * CH;
  const unsigned short* wl0 = WTl + (long)(w * 64 + l31) * CH;
  f32x16 acc0, acc1;
#pragma unroll
  for (int i = 0; i < 16; ++i) { acc0[i] = 0.f; acc1[i] = 0.f; }
#pragma unroll
  for (int s = 0; s < 16; ++s) {
    const int koff = lh * 8 + s * 16;
    bf16x8 beh = *(const bf16x8*)&ldsH[s * 512 + lane * 8];
    bf16x8 bel = *(const bf16x8*)&ldsL[s * 512 + lane * 8];
    bf16x8 ah0 = *(const bf16x8*)(const __bf16*)(wh0 + koff);
    bf16x8 al0 = *(const bf16x8*)(const __bf16*)(wl0 + koff);
    bf16x8 ah1 = *(const bf16x8*)(const __bf16*)(wh0 + 32 * CH + koff);
    bf16x8 al1 = *(const bf16x8*)(const __bf16*)(wl0 + 32 * CH + koff);
    acc0 = __builtin_amdgcn_mfma_f32_32x32x16_bf16(ah0, beh, acc0, 0, 0, 0);
    acc1 = __builtin_amdgcn_mfma_f32_32x32x16_bf16(ah1, beh, acc1, 0, 0, 0);
    acc0 = __builtin_amdgcn_mfma_f32_32x32x16_bf16(al0, beh, acc0, 0, 0, 0);
    acc1 = __builtin_amdgcn_mfma_f32_32x32x16_bf16(al1, beh, acc1, 0, 0, 0);
    acc0 = __builtin_amdgcn_mfma_f32_32x32x16_bf16(ah0, bel, acc0, 0, 0, 0);
    acc1 = __builtin_amdgcn_mfma_f32_32x32x16_bf16(ah1, bel, acc1, 0, 0, 0);
  }
  __syncthreads();   // staging reads done; smem reusable as S

  float* S = (float*)smem;               // [256][33]
  float* ot = out_t + (long)b * CH * NT + m0;
#pragma unroll
  for (int reg = 0; reg < 16; ++reg) {
    const int row = (reg & 3) + 8 * (reg >> 2) + 4 * lh;
    const int ch0 = w * 64 + row, ch1 = ch0 + 32;
    float v0 = acc0[reg] + bias[ch0];
    float v1 = acc1[reg] + bias[ch1];
    S[ch0 * 33 + l31] = v0;
    S[ch1 * 33 + l31] = v1;
    ot[(long)ch0 * NT + l31] = v0;
    ot[(long)ch1 * NT + l31] = v1;
  }
  __syncthreads();

  // scatter: per node nn, all 256 threads = 256 channels, coalesced atomics
  float* cb = contrib + (long)b * NCTX * CH;
#pragma unroll 4
  for (int nn = 0; nn < 32; ++nn) {
    float v = S[t * 33 + nn];
    const int* kn = &knns[nn * 8];
#pragma unroll
    for (int q = 0; q < KI; ++q)
      atomicAdd(&cb[(long)kn[q] * CH + t], v);
  }
}

// ---------------- finalize context outputs: /counts, transpose (128-j tiles, float4 stores) ----------------
__global__ __launch_bounds__(256) void k_fin_c(const float* __restrict__ contrib,
                                               const unsigned* __restrict__ counts,
                                               float* __restrict__ out1,
                                               float* __restrict__ out2) {
  __shared__ float tile[128][33];
  const int b = blockIdx.z;
  const int j0 = blockIdx.x * 128, c0 = blockIdx.y * 32;
  const int tx = threadIdx.x, ty = threadIdx.y;
#pragma unroll
  for (int i = ty; i < 128; i += 8) {
    float cnt = fmaxf((float)counts[(long)b * NCTX + j0 + i], 1.0f);
    tile[i][tx] = contrib[((long)b * NCTX + j0 + i) * CH + c0 + tx] * (1.0f / cnt);
  }
  __syncthreads();
  float* outp = (j0 < NT) ? (out1 + (long)b * CH * NT + j0)
                          : (out2 + (long)b * CH * NT + (j0 - NT));
#pragma unroll
  for (int i = ty; i < 32; i += 8) {
    float4 v;
    v.x = tile[4 * tx + 0][i];
    v.y = tile[4 * tx + 1][i];
    v.z = tile[4 * tx + 2][i];
    v.w = tile[4 * tx + 3][i];
    *(float4*)&outp[(long)(c0 + i) * NT + 4 * tx] = v;
  }
}

extern "C" void kernel_launch(void* const* d_in, const int* in_sizes, int n_in,
                              void* d_out, int out_size, void* d_ws, size_t ws_size,
                              hipStream_t stream) {
  const float* Xt  = (const float*)d_in[0];
  const float* Xc1 = (const float*)d_in[1];
  const float* Xc2 = (const float*)d_in[2];
  const float* W1  = (const float*)d_in[3];
  const float* b1  = (const float*)d_in[4];
  const float* W2  = (const float*)d_in[5];
  const float* b2  = (const float*)d_in[6];
  float* out = (float*)d_out;

  // common ws layout (68.42 MB)
  float* P = (float*)d_ws;                               // XcT -> (fallback Xn_c) -> contrib
  float* Q = P + (long)BATCH * NCTX * CH;                // XtT -> Xe (row-interleaved, in-place)
  float* R = Q + (long)BATCH * NT * CH;                  // (fallback cand) -> Xn_t
  float* nrm = R + (long)BATCH * NT * CH;
  unsigned* counts = (unsigned*)(nrm + (long)BATCH * NCTX);
  int* knn = (int*)(counts + (long)BATCH * NCTX);
  unsigned short* WT1h = (unsigned short*)(knn + (long)BATCH * NT * KI);
  unsigned short* WT1l = WT1h + CH * CH;
  unsigned short* WT2h = WT1l + CH * CH;
  unsigned short* WT2l = WT2h + CH * CH;
  // fat-mode extras: separate Xn_c (33.55 MB) + cand (5.24 MB)
  float* Xn_c_fat = (float*)(WT2l + CH * CH);
  unsigned* cand_fat = (unsigned*)(Xn_c_fat + (long)BATCH * NCTX * CH);
  const size_t need_fat = (size_t)((char*)(cand_fat + (long)BATCH * NT * NKEY) - (char*)d_ws);
  const bool fat = ws_size >= need_fat;

  unsigned* cand = fat ? cand_fat : (unsigned*)R;
  float* Xn_c = fat ? Xn_c_fat : P;
  float* Xn_t = R;

  unsigned short* XcBh = (unsigned short*)d_out;
  unsigned short* XtBh = XcBh + (long)BATCH * NCTX * CH;
  unsigned short* XcBl = XtBh + (long)BATCH * NT * CH;
  unsigned short* XtBl = XcBl + (long)BATCH * NCTX * CH;

  unsigned short* XeHL = (unsigned short*)Q;   // Xe overwrites Q row-for-row (1KB rows)

  float* out_t  = out;             // overwrites dead XcBh region
  float* out_c1 = out + (long)BATCH * CH * NT;
  float* out_c2 = out + 2L * BATCH * CH * NT;

  dim3 tb(32, 8);

  hipMemsetAsync(nrm, 0, (size_t)BATCH * NCTX * 8, stream);   // nrm + counts

  k_prep<<<dim3(3072 + 128), tb, 0, stream>>>(Xt, Xc1, Xc2, Q, P, XtBh, XtBl, XcBh, XcBl, nrm,
                                              W1, W2, WT1h, WT1l, WT2h, WT2l);

  if (fat) {
    // dist (XCD-correct bids 0..1023) + both node2edge GEMMs queued behind (R12-proven layout)
    k_main<<<dim3(1024 + 512 + 1024), 256, 0, stream>>>(
        (const __bf16*)XcBh, (const __bf16*)XtBh, nrm, cand,
        XtBh, XtBl, XcBh, XcBl, WT1h, WT1l, b1, Xn_t, Xn_c);
    // rescore (fp32 inputs, bit-identical to R16) + fused gather (row-exact Q overwrite)
    k_rescore<<<dim3(NT / 4, BATCH), 256, 0, stream>>>(
        Q, P, cand, knn, counts, Xn_t, Xn_c, XeHL, 1);
  } else {
    k_main<<<dim3(1024), 256, 0, stream>>>(
        (const __bf16*)XcBh, (const __bf16*)XtBh, nrm, cand,
        XtBh, XtBl, XcBh, XcBl, WT1h, WT1l, b1, Xn_t, Xn_c);
    k_rescore<<<dim3(NT / 4, BATCH), 256, 0, stream>>>(
        Q, P, cand, knn, counts, Xn_t, Xn_c, XeHL, 0);
    k_gemm_mfma<<<dim3(NT / 32, BATCH), 256, 0, stream>>>(XtBh, XtBl, WT1h, WT1l, b1, Xn_t, NT);
    k_gemm_mfma<<<dim3(NCTX / 32, BATCH), 256, 0, stream>>>(XcBh, XcBl, WT1h, WT1l, b1, Xn_c, NCTX);
    k_gather<<<dim3(NT, BATCH), 256, 0, stream>>>(Xn_t, Xn_c, knn, XeHL);
  }

  // P dead now -> contrib
  hipMemsetAsync(P, 0, (size_t)BATCH * NCTX * CH * 4, stream);

  // fused edge2node + out_t + scatter atomics
  k_g2f<<<dim3(NT / 32, BATCH), 256, 0, stream>>>(XeHL, WT2h, WT2l, b2, knn, out_t, P);

  k_fin_c<<<dim3(NCTX / 128, CH / 32, BATCH), tb, 0, stream>>>(P, counts, out_c1, out_c2);
}